// Round 1
// baseline (397.940 us; speedup 1.0000x reference)
//
#include <hip/hip_runtime.h>

// Problem constants
#define BB  2
#define CC  256
#define LL  4096   // 64*64 spatial tokens
#define NHD 2
#define DKD 128
#define DVD 128

// Workspace layout (assumes ws_size >= ~34 MB):
//   qn  : bf16 [B][NH][L][DK]   (l2-normalized, * sqrt(scale))
//   kn  : bf16 [B][NH][L][DK]
//   vb  : bf16 [B][NH][DV][L]
//   rb  : bf16 [B][NH*DV][L]    (attention output, pre-merge)

typedef short  short8  __attribute__((ext_vector_type(8)));
typedef float  f32x4   __attribute__((ext_vector_type(4)));
typedef unsigned short ushort4v __attribute__((ext_vector_type(4)));

__device__ __forceinline__ unsigned short f2bf(float f) {
  union { float f; unsigned u; } v; v.f = f;
  unsigned r = v.u + 0x7fffu + ((v.u >> 16) & 1u);   // RNE
  return (unsigned short)(r >> 16);
}
__device__ __forceinline__ float bf2f(unsigned short u) {
  union { unsigned u; float f; } v; v.u = ((unsigned)u) << 16;
  return v.f;
}

// ---------------------------------------------------------------------------
// Kernel 1: QKV 1x1-conv projections (fp32), fused l2-norm for Q/K, bf16 out.
// grid (L/32, B*NH, 3)  block 256.  Tile: full 128 k-rows x 32 l-cols.
// Thread (tk,tl) = (tid>>4, tid&15): rows tk*8..tk*8+7, cols tl*2, tl*2+1.
// ---------------------------------------------------------------------------
__global__ __launch_bounds__(256) void mhsa_proj_kernel(
    const float* __restrict__ x,
    const float* __restrict__ Wq, const float* __restrict__ bq,
    const float* __restrict__ Wk, const float* __restrict__ bk,
    const float* __restrict__ Wv, const float* __restrict__ bv,
    const float* __restrict__ scale,
    unsigned short* __restrict__ qn,
    unsigned short* __restrict__ kn,
    unsigned short* __restrict__ vb)
{
  const int lt = blockIdx.x * 32;
  const int bh = blockIdx.y;           // b*NH + h
  const int h  = bh % NHD;
  const int b  = bh / NHD;
  const int p  = blockIdx.z;           // 0=Q 1=K 2=V

  const float* W    = (p == 0 ? Wq : (p == 1 ? Wk : Wv)) + (size_t)h * DKD * CC;
  const float* bias = (p == 0 ? bq : (p == 1 ? bk : bv)) + h * DKD;

  __shared__ float WsT[32][132];   // [c][k], transposed W tile (+pad)
  __shared__ float Xs[32][33];     // [c][l]
  __shared__ float red[16][32];
  __shared__ float ninv[32];

  const int tid = threadIdx.x;
  const int tk  = tid >> 4;   // 0..15
  const int tl  = tid & 15;   // 0..15

  float acc[8][2];
  #pragma unroll
  for (int r = 0; r < 8; ++r) { acc[r][0] = 0.f; acc[r][1] = 0.f; }

  const float* xb = x + (size_t)b * CC * LL;

  for (int c0 = 0; c0 < CC; c0 += 32) {
    __syncthreads();
    #pragma unroll
    for (int i = 0; i < 16; ++i) {              // 128x32 W tile -> WsT[c][k]
      int flat = tid + 256 * i;
      int k = flat >> 5, c = flat & 31;
      WsT[c][k] = W[(size_t)k * CC + c0 + c];
    }
    #pragma unroll
    for (int i = 0; i < 4; ++i) {               // 32x32 x tile
      int flat = tid + 256 * i;
      int c = flat >> 5, l = flat & 31;
      Xs[c][l] = xb[(size_t)(c0 + c) * LL + lt + l];
    }
    __syncthreads();
    #pragma unroll 8
    for (int cc = 0; cc < 32; ++cc) {
      float x0 = Xs[cc][tl * 2 + 0];
      float x1 = Xs[cc][tl * 2 + 1];
      f32x4 w0 = *(const f32x4*)&WsT[cc][tk * 8 + 0];
      f32x4 w1 = *(const f32x4*)&WsT[cc][tk * 8 + 4];
      #pragma unroll
      for (int r = 0; r < 4; ++r) {
        acc[r][0]     += w0[r] * x0;  acc[r][1]     += w0[r] * x1;
        acc[r + 4][0] += w1[r] * x0;  acc[r + 4][1] += w1[r] * x1;
      }
    }
  }

  #pragma unroll
  for (int r = 0; r < 8; ++r) {
    float bs = bias[tk * 8 + r];
    acc[r][0] += bs;  acc[r][1] += bs;
  }

  if (p < 2) {
    // column l2-norm over full DK=128
    float s0 = 0.f, s1 = 0.f;
    #pragma unroll
    for (int r = 0; r < 8; ++r) { s0 += acc[r][0] * acc[r][0]; s1 += acc[r][1] * acc[r][1]; }
    __syncthreads();
    red[tk][tl * 2 + 0] = s0;
    red[tk][tl * 2 + 1] = s1;
    __syncthreads();
    if (tid < 32) {
      float s = 0.f;
      #pragma unroll
      for (int i = 0; i < 16; ++i) s += red[i][tid];
      ninv[tid] = sqrtf(scale[h]) / fmaxf(sqrtf(s), 1e-6f);
    }
    __syncthreads();
    unsigned short* out = (p == 0 ? qn : kn) + ((size_t)bh * LL + lt) * DKD;
    float n0 = ninv[tl * 2 + 0], n1 = ninv[tl * 2 + 1];
    #pragma unroll
    for (int j = 0; j < 2; ++j) {
      float nv = j ? n1 : n0;
      short8 pk;
      #pragma unroll
      for (int r = 0; r < 8; ++r) pk[r] = (short)f2bf(acc[r][j] * nv);
      *reinterpret_cast<short8*>(out + (size_t)(tl * 2 + j) * DKD + tk * 8) = pk;
    }
  } else {
    unsigned short* out = vb + (size_t)bh * DVD * LL;
    #pragma unroll
    for (int r = 0; r < 8; ++r) {
      unsigned pk = (unsigned)f2bf(acc[r][0]) | ((unsigned)f2bf(acc[r][1]) << 16);
      *reinterpret_cast<unsigned*>(out + (size_t)(tk * 8 + r) * LL + lt + tl * 2) = pk;
    }
  }
}

// ---------------------------------------------------------------------------
// Kernel 2: flash attention, bf16 MFMA 16x16x32.
// grid (L/64, B*NH)  block 256 (4 waves); each wave owns 16 q-rows.
// S = Qn.Kn^T (cosine*scale), online softmax, R = P.V^T.
// Fragment maps (m89-verified): A row=lane&15, k=(lane>>4)*8+j contiguous;
// B col=lane&15, same k; D col=lane&15, row=(lane>>4)*4+reg.
// ---------------------------------------------------------------------------
__global__ __launch_bounds__(256) void mhsa_attn_kernel(
    const unsigned short* __restrict__ qn,
    const unsigned short* __restrict__ kn,
    const unsigned short* __restrict__ vb,
    unsigned short* __restrict__ rb)
{
  const int bh   = blockIdx.y;
  const int wave = threadIdx.x >> 6;
  const int lane = threadIdx.x & 63;
  const int l0   = blockIdx.x * 64 + wave * 16;

  const unsigned short* Q = qn + (size_t)bh * LL * DKD;
  const unsigned short* K = kn + (size_t)bh * LL * DKD;
  const unsigned short* V = vb + (size_t)bh * DVD * LL;

  const int lr = lane & 15;
  const int lc = lane >> 4;

  __shared__ unsigned short plds[4][16][72];   // per-wave P tile, +8 bf16 pad

  short8 qf[4];
  #pragma unroll
  for (int ks = 0; ks < 4; ++ks)
    qf[ks] = *reinterpret_cast<const short8*>(Q + (size_t)(l0 + lr) * DKD + ks * 32 + lc * 8);

  f32x4 racc[8];
  #pragma unroll
  for (int vt = 0; vt < 8; ++vt) racc[vt] = (f32x4){0.f, 0.f, 0.f, 0.f};
  float mrun[4], lrun[4];
  #pragma unroll
  for (int r = 0; r < 4; ++r) { mrun[r] = -1e30f; lrun[r] = 0.f; }

  for (int m0 = 0; m0 < LL; m0 += 64) {
    // ---- S tile: 16 q-rows x 64 keys ----
    f32x4 s[4];
    #pragma unroll
    for (int ct = 0; ct < 4; ++ct) {
      f32x4 acc = (f32x4){0.f, 0.f, 0.f, 0.f};
      #pragma unroll
      for (int ks = 0; ks < 4; ++ks) {
        short8 kf = *reinterpret_cast<const short8*>(
            K + (size_t)(m0 + ct * 16 + lr) * DKD + ks * 32 + lc * 8);
        acc = __builtin_amdgcn_mfma_f32_16x16x32_bf16(qf[ks], kf, acc, 0, 0, 0);
      }
      s[ct] = acc;
    }
    // ---- online softmax (row l = l0 + lc*4 + r) ----
    #pragma unroll
    for (int r = 0; r < 4; ++r) {
      float tm = fmaxf(fmaxf(s[0][r], s[1][r]), fmaxf(s[2][r], s[3][r]));
      #pragma unroll
      for (int msk = 8; msk; msk >>= 1) tm = fmaxf(tm, __shfl_xor(tm, msk, 64));
      float nm  = fmaxf(mrun[r], tm);
      float fac = __expf(mrun[r] - nm);
      float ps  = 0.f;
      #pragma unroll
      for (int ct = 0; ct < 4; ++ct) {
        float pv = __expf(s[ct][r] - nm);
        s[ct][r] = pv;
        ps += pv;
      }
      #pragma unroll
      for (int msk = 8; msk; msk >>= 1) ps += __shfl_xor(ps, msk, 64);
      lrun[r] = lrun[r] * fac + ps;
      mrun[r] = nm;
      #pragma unroll
      for (int vt = 0; vt < 8; ++vt) racc[vt][r] *= fac;
    }
    // ---- P -> LDS (bf16), re-layout D-frag to A-frag ----
    #pragma unroll
    for (int ct = 0; ct < 4; ++ct)
      #pragma unroll
      for (int r = 0; r < 4; ++r)
        plds[wave][lc * 4 + r][ct * 16 + lr] = f2bf(s[ct][r]);

    short8 pf[2];
    #pragma unroll
    for (int ks = 0; ks < 2; ++ks)
      pf[ks] = *reinterpret_cast<const short8*>(&plds[wave][lr][ks * 32 + lc * 8]);

    // ---- PV: racc[vt] += P[16x64] . V^T[64x16] ----
    #pragma unroll
    for (int vt = 0; vt < 8; ++vt) {
      #pragma unroll
      for (int ks = 0; ks < 2; ++ks) {
        short8 vf = *reinterpret_cast<const short8*>(
            V + (size_t)(vt * 16 + lr) * LL + m0 + ks * 32 + lc * 8);
        racc[vt] = __builtin_amdgcn_mfma_f32_16x16x32_bf16(pf[ks], vf, racc[vt], 0, 0, 0);
      }
    }
  }

  // ---- finalize: R/l, write bf16 [B][NH*DV][L] ----
  float inv[4];
  #pragma unroll
  for (int r = 0; r < 4; ++r) inv[r] = 1.f / lrun[r];
  unsigned short* Rb = rb + (size_t)bh * DVD * LL;
  #pragma unroll
  for (int vt = 0; vt < 8; ++vt) {
    ushort4v pk;
    #pragma unroll
    for (int r = 0; r < 4; ++r) pk[r] = f2bf(racc[vt][r] * inv[r]);
    *reinterpret_cast<ushort4v*>(Rb + (size_t)(vt * 16 + lr) * LL + l0 + lc * 4) = pk;
  }
}

// ---------------------------------------------------------------------------
// Kernel 3: merge 1x1 conv + bias + residual (fp32).
// grid (L/64, C/64, B)  block 256; thread computes 4x4 outputs.
// ---------------------------------------------------------------------------
__global__ __launch_bounds__(256) void mhsa_merge_kernel(
    const unsigned short* __restrict__ rb,
    const float* __restrict__ Wm,
    const float* __restrict__ bm,
    const float* __restrict__ x,
    float* __restrict__ out)
{
  const int l0 = blockIdx.x * 64;
  const int o0 = blockIdx.y * 64;
  const int b  = blockIdx.z;

  __shared__ float WmT[32][68];  // [c][o]
  __shared__ float Rs[32][68];   // [c][l]

  const int tid = threadIdx.x;
  const int to  = tid >> 4;
  const int tl  = tid & 15;

  float acc[4][4];
  #pragma unroll
  for (int r = 0; r < 4; ++r)
    #pragma unroll
    for (int j = 0; j < 4; ++j) acc[r][j] = 0.f;

  for (int c0 = 0; c0 < CC; c0 += 32) {
    __syncthreads();
    #pragma unroll
    for (int i = 0; i < 8; ++i) {              // 64x32 Wm tile -> WmT[c][o]
      int flat = tid + 256 * i;
      int o = flat >> 5, c = flat & 31;
      WmT[c][o] = Wm[(size_t)(o0 + o) * CC + c0 + c];
    }
    #pragma unroll
    for (int i = 0; i < 8; ++i) {              // 32x64 R tile
      int flat = tid + 256 * i;
      int c = flat >> 6, l = flat & 63;
      Rs[c][l] = bf2f(rb[((size_t)b * CC + c0 + c) * LL + l0 + l]);
    }
    __syncthreads();
    #pragma unroll 4
    for (int cc = 0; cc < 32; ++cc) {
      f32x4 wv = *(const f32x4*)&WmT[cc][to * 4];
      f32x4 rv = *(const f32x4*)&Rs[cc][tl * 4];
      #pragma unroll
      for (int r = 0; r < 4; ++r)
        #pragma unroll
        for (int j = 0; j < 4; ++j) acc[r][j] += wv[r] * rv[j];
    }
  }

  #pragma unroll
  for (int r = 0; r < 4; ++r) {
    int o = o0 + to * 4 + r;
    float bias = bm[o];
    size_t off = ((size_t)b * CC + o) * LL + l0 + tl * 4;
    f32x4 xv = *reinterpret_cast<const f32x4*>(x + off);
    f32x4 ov;
    #pragma unroll
    for (int j = 0; j < 4; ++j) ov[j] = acc[r][j] + bias + xv[j];
    *reinterpret_cast<f32x4*>(out + off) = ov;
  }
}

// ---------------------------------------------------------------------------
extern "C" void kernel_launch(void* const* d_in, const int* in_sizes, int n_in,
                              void* d_out, int out_size, void* d_ws, size_t ws_size,
                              hipStream_t stream) {
  const float* x     = (const float*)d_in[0];
  const float* Wq    = (const float*)d_in[1];
  const float* bq    = (const float*)d_in[2];
  const float* Wk    = (const float*)d_in[3];
  const float* bk    = (const float*)d_in[4];
  const float* Wv    = (const float*)d_in[5];
  const float* bv    = (const float*)d_in[6];
  const float* scale = (const float*)d_in[7];
  const float* Wm    = (const float*)d_in[8];
  const float* bm    = (const float*)d_in[9];
  float* out = (float*)d_out;

  const size_t nqk = (size_t)BB * NHD * LL * DKD;   // elements per q/k/v buffer
  unsigned short* qn = (unsigned short*)d_ws;
  unsigned short* kn = qn + nqk;
  unsigned short* vb = kn + nqk;
  unsigned short* rb = vb + nqk;                    // [B][NH*DV][L]

  mhsa_proj_kernel<<<dim3(LL / 32, BB * NHD, 3), dim3(256), 0, stream>>>(
      x, Wq, bq, Wk, bk, Wv, bv, scale, qn, kn, vb);
  mhsa_attn_kernel<<<dim3(LL / 64, BB * NHD), dim3(256), 0, stream>>>(qn, kn, vb, rb);
  mhsa_merge_kernel<<<dim3(LL / 64, CC / 64, BB), dim3(256), 0, stream>>>(
      rb, Wm, bm, x, out);
}

// Round 2
// 333.553 us; speedup vs baseline: 1.1930x; 1.1930x over previous
//
#include <hip/hip_runtime.h>

// Problem constants
#define BB  2
#define CC  256
#define LL  4096   // 64*64 spatial tokens
#define NHD 2
#define DKD 128
#define DVD 128

// Workspace layout (assumes ws_size >= ~34 MB):
//   qn  : bf16 [B][NH][L][DK]   (l2-normalized, * sqrt(scale))
//   kn  : bf16 [B][NH][L][DK]
//   vb  : bf16 [B][NH][DV][L]
//   rb  : bf16 [B][NH*DV][L]    (attention output, pre-merge)

typedef short  short8  __attribute__((ext_vector_type(8)));
typedef float  f32x4   __attribute__((ext_vector_type(4)));
typedef unsigned short ushort4v __attribute__((ext_vector_type(4)));

__device__ __forceinline__ unsigned short f2bf(float f) {
  union { float f; unsigned u; } v; v.f = f;
  unsigned r = v.u + 0x7fffu + ((v.u >> 16) & 1u);   // RNE
  return (unsigned short)(r >> 16);
}
__device__ __forceinline__ float bf2f(unsigned short u) {
  union { unsigned u; float f; } v; v.u = ((unsigned)u) << 16;
  return v.f;
}

// ---------------------------------------------------------------------------
// Kernel 1: QKV 1x1-conv projections (fp32), fused l2-norm for Q/K, bf16 out.
// grid (L/32, B*NH, 3)  block 256.  Tile: full 128 k-rows x 32 l-cols.
// ---------------------------------------------------------------------------
__global__ __launch_bounds__(256) void mhsa_proj_kernel(
    const float* __restrict__ x,
    const float* __restrict__ Wq, const float* __restrict__ bq,
    const float* __restrict__ Wk, const float* __restrict__ bk,
    const float* __restrict__ Wv, const float* __restrict__ bv,
    const float* __restrict__ scale,
    unsigned short* __restrict__ qn,
    unsigned short* __restrict__ kn,
    unsigned short* __restrict__ vb)
{
  const int lt = blockIdx.x * 32;
  const int bh = blockIdx.y;           // b*NH + h
  const int h  = bh % NHD;
  const int b  = bh / NHD;
  const int p  = blockIdx.z;           // 0=Q 1=K 2=V

  const float* W    = (p == 0 ? Wq : (p == 1 ? Wk : Wv)) + (size_t)h * DKD * CC;
  const float* bias = (p == 0 ? bq : (p == 1 ? bk : bv)) + h * DKD;

  __shared__ float WsT[32][132];   // [c][k], transposed W tile (+pad)
  __shared__ float Xs[32][33];     // [c][l]
  __shared__ float red[16][32];
  __shared__ float ninv[32];

  const int tid = threadIdx.x;
  const int tk  = tid >> 4;   // 0..15
  const int tl  = tid & 15;   // 0..15

  float acc[8][2];
  #pragma unroll
  for (int r = 0; r < 8; ++r) { acc[r][0] = 0.f; acc[r][1] = 0.f; }

  const float* xb = x + (size_t)b * CC * LL;

  for (int c0 = 0; c0 < CC; c0 += 32) {
    __syncthreads();
    #pragma unroll
    for (int i = 0; i < 16; ++i) {              // 128x32 W tile -> WsT[c][k]
      int flat = tid + 256 * i;
      int k = flat >> 5, c = flat & 31;
      WsT[c][k] = W[(size_t)k * CC + c0 + c];
    }
    #pragma unroll
    for (int i = 0; i < 4; ++i) {               // 32x32 x tile
      int flat = tid + 256 * i;
      int c = flat >> 5, l = flat & 31;
      Xs[c][l] = xb[(size_t)(c0 + c) * LL + lt + l];
    }
    __syncthreads();
    #pragma unroll 8
    for (int cc = 0; cc < 32; ++cc) {
      float x0 = Xs[cc][tl * 2 + 0];
      float x1 = Xs[cc][tl * 2 + 1];
      f32x4 w0 = *(const f32x4*)&WsT[cc][tk * 8 + 0];
      f32x4 w1 = *(const f32x4*)&WsT[cc][tk * 8 + 4];
      #pragma unroll
      for (int r = 0; r < 4; ++r) {
        acc[r][0]     += w0[r] * x0;  acc[r][1]     += w0[r] * x1;
        acc[r + 4][0] += w1[r] * x0;  acc[r + 4][1] += w1[r] * x1;
      }
    }
  }

  #pragma unroll
  for (int r = 0; r < 8; ++r) {
    float bs = bias[tk * 8 + r];
    acc[r][0] += bs;  acc[r][1] += bs;
  }

  if (p < 2) {
    // column l2-norm over full DK=128
    float s0 = 0.f, s1 = 0.f;
    #pragma unroll
    for (int r = 0; r < 8; ++r) { s0 += acc[r][0] * acc[r][0]; s1 += acc[r][1] * acc[r][1]; }
    __syncthreads();
    red[tk][tl * 2 + 0] = s0;
    red[tk][tl * 2 + 1] = s1;
    __syncthreads();
    if (tid < 32) {
      float s = 0.f;
      #pragma unroll
      for (int i = 0; i < 16; ++i) s += red[i][tid];
      ninv[tid] = sqrtf(scale[h]) / fmaxf(sqrtf(s), 1e-6f);
    }
    __syncthreads();
    unsigned short* out = (p == 0 ? qn : kn) + ((size_t)bh * LL + lt) * DKD;
    float n0 = ninv[tl * 2 + 0], n1 = ninv[tl * 2 + 1];
    #pragma unroll
    for (int j = 0; j < 2; ++j) {
      float nv = j ? n1 : n0;
      short8 pk;
      #pragma unroll
      for (int r = 0; r < 8; ++r) pk[r] = (short)f2bf(acc[r][j] * nv);
      *reinterpret_cast<short8*>(out + (size_t)(tl * 2 + j) * DKD + tk * 8) = pk;
    }
  } else {
    unsigned short* out = vb + (size_t)bh * DVD * LL;
    #pragma unroll
    for (int r = 0; r < 8; ++r) {
      unsigned pk = (unsigned)f2bf(acc[r][0]) | ((unsigned)f2bf(acc[r][1]) << 16);
      *reinterpret_cast<unsigned*>(out + (size_t)(tk * 8 + r) * LL + lt + tl * 2) = pk;
    }
  }
}

// ---------------------------------------------------------------------------
// Kernel 2: flash attention, bf16 MFMA 16x16x32, split-K within block.
// grid (L/16, B*NH)  block 256 (4 waves). One block = one 16-row q-tile;
// wave w handles keys [w*1024, w*1024+1024), then LDS flash-combine.
// Fragment maps (m89-verified): A row=lane&15, k=(lane>>4)*8+j contiguous;
// B col=lane&15, same k; D col=lane&15, row=(lane>>4)*4+reg.
// LDS: per-wave scratch unions the P-staging tile (main loop, 2304 B) with
// the fp32 partial-result tile for the combine (8448 B). Each wave touches
// only its own region until the single __syncthreads().
// ---------------------------------------------------------------------------
#define KCHUNK (LL / 4)   // 1024 keys per wave

__global__ __launch_bounds__(256) void mhsa_attn_kernel(
    const unsigned short* __restrict__ qn,
    const unsigned short* __restrict__ kn,
    const unsigned short* __restrict__ vb,
    unsigned short* __restrict__ rb)
{
  const int bh   = blockIdx.y;
  const int wave = threadIdx.x >> 6;
  const int lane = threadIdx.x & 63;
  const int tid  = threadIdx.x;
  const int l0   = blockIdx.x * 16;

  const unsigned short* Q = qn + (size_t)bh * LL * DKD;
  const unsigned short* K = kn + (size_t)bh * LL * DKD;
  const unsigned short* V = vb + (size_t)bh * DVD * LL;

  const int lr = lane & 15;
  const int lc = lane >> 4;

  // per-wave union scratch: plds (ushort[16][72]) overlays raccl (float[16][132])
  __shared__ float wscratch[4][16 * 132];          // 33792 B
  __shared__ float ml_lds[4][2][16];               // [wave][m/l][row]
  float* myscr = wscratch[wave];
  unsigned short* plds = (unsigned short*)myscr;   // [16][72]

  short8 qf[4];
  #pragma unroll
  for (int ks = 0; ks < 4; ++ks)
    qf[ks] = *reinterpret_cast<const short8*>(Q + (size_t)(l0 + lr) * DKD + ks * 32 + lc * 8);

  f32x4 racc[8];
  #pragma unroll
  for (int vt = 0; vt < 8; ++vt) racc[vt] = (f32x4){0.f, 0.f, 0.f, 0.f};
  float mrun[4], lrun[4];
  #pragma unroll
  for (int r = 0; r < 4; ++r) { mrun[r] = -1e30f; lrun[r] = 0.f; }

  const int mbeg = wave * KCHUNK;
  for (int m0 = mbeg; m0 < mbeg + KCHUNK; m0 += 64) {
    // ---- S tile: 16 q-rows x 64 keys ----
    f32x4 s[4];
    #pragma unroll
    for (int ct = 0; ct < 4; ++ct) {
      f32x4 acc = (f32x4){0.f, 0.f, 0.f, 0.f};
      #pragma unroll
      for (int ks = 0; ks < 4; ++ks) {
        short8 kf = *reinterpret_cast<const short8*>(
            K + (size_t)(m0 + ct * 16 + lr) * DKD + ks * 32 + lc * 8);
        acc = __builtin_amdgcn_mfma_f32_16x16x32_bf16(qf[ks], kf, acc, 0, 0, 0);
      }
      s[ct] = acc;
    }
    // ---- online softmax (row = lc*4 + r) ----
    #pragma unroll
    for (int r = 0; r < 4; ++r) {
      float tm = fmaxf(fmaxf(s[0][r], s[1][r]), fmaxf(s[2][r], s[3][r]));
      #pragma unroll
      for (int msk = 8; msk; msk >>= 1) tm = fmaxf(tm, __shfl_xor(tm, msk, 64));
      float nm  = fmaxf(mrun[r], tm);
      float fac = __expf(mrun[r] - nm);
      float ps  = 0.f;
      #pragma unroll
      for (int ct = 0; ct < 4; ++ct) {
        float pv = __expf(s[ct][r] - nm);
        s[ct][r] = pv;
        ps += pv;
      }
      #pragma unroll
      for (int msk = 8; msk; msk >>= 1) ps += __shfl_xor(ps, msk, 64);
      lrun[r] = lrun[r] * fac + ps;
      mrun[r] = nm;
      #pragma unroll
      for (int vt = 0; vt < 8; ++vt) racc[vt][r] *= fac;
    }
    // ---- P -> LDS (bf16), re-layout D-frag to A-frag (per-wave, no barrier) ----
    #pragma unroll
    for (int ct = 0; ct < 4; ++ct)
      #pragma unroll
      for (int r = 0; r < 4; ++r)
        plds[(lc * 4 + r) * 72 + ct * 16 + lr] = f2bf(s[ct][r]);

    short8 pf[2];
    #pragma unroll
    for (int ks = 0; ks < 2; ++ks)
      pf[ks] = *reinterpret_cast<const short8*>(&plds[lr * 72 + ks * 32 + lc * 8]);

    // ---- PV: racc[vt] += P[16x64] . V^T[64x16] ----
    #pragma unroll
    for (int vt = 0; vt < 8; ++vt) {
      #pragma unroll
      for (int ks = 0; ks < 2; ++ks) {
        short8 vf = *reinterpret_cast<const short8*>(
            V + (size_t)(vt * 16 + lr) * LL + m0 + ks * 32 + lc * 8);
        racc[vt] = __builtin_amdgcn_mfma_f32_16x16x32_bf16(pf[ks], vf, racc[vt], 0, 0, 0);
      }
    }
  }

  // ---- dump partials to LDS (overlays plds; within-wave LDS ops are ordered) ----
  #pragma unroll
  for (int vt = 0; vt < 8; ++vt)
    #pragma unroll
    for (int r = 0; r < 4; ++r)
      myscr[(lc * 4 + r) * 132 + vt * 16 + lr] = racc[vt][r];
  if (lr == 0) {
    #pragma unroll
    for (int r = 0; r < 4; ++r) {
      ml_lds[wave][0][lc * 4 + r] = mrun[r];
      ml_lds[wave][1][lc * 4 + r] = lrun[r];
    }
  }
  __syncthreads();

  // ---- flash-combine across the 4 waves ----
  const int q  = tid & 15;        // q-row within tile
  const int vb0 = tid >> 4;       // 0..15
  float m0 = ml_lds[0][0][q], m1 = ml_lds[1][0][q];
  float m2 = ml_lds[2][0][q], m3 = ml_lds[3][0][q];
  float M = fmaxf(fmaxf(m0, m1), fmaxf(m2, m3));
  float a0 = __expf(m0 - M), a1 = __expf(m1 - M);
  float a2 = __expf(m2 - M), a3 = __expf(m3 - M);
  float Ls = a0 * ml_lds[0][1][q] + a1 * ml_lds[1][1][q]
           + a2 * ml_lds[2][1][q] + a3 * ml_lds[3][1][q];
  float invL = 1.f / Ls;
  unsigned short* Rb = rb + (size_t)bh * DVD * LL;
  #pragma unroll
  for (int it = 0; it < 8; ++it) {
    int v = it * 16 + vb0;
    float sacc = a0 * wscratch[0][q * 132 + v] + a1 * wscratch[1][q * 132 + v]
               + a2 * wscratch[2][q * 132 + v] + a3 * wscratch[3][q * 132 + v];
    Rb[(size_t)v * LL + l0 + q] = f2bf(sacc * invL);
  }
}

// ---------------------------------------------------------------------------
// Kernel 3: merge 1x1 conv + bias + residual (fp32).
// grid (L/64, C/64, B)  block 256; thread computes 4x4 outputs.
// ---------------------------------------------------------------------------
__global__ __launch_bounds__(256) void mhsa_merge_kernel(
    const unsigned short* __restrict__ rb,
    const float* __restrict__ Wm,
    const float* __restrict__ bm,
    const float* __restrict__ x,
    float* __restrict__ out)
{
  const int l0 = blockIdx.x * 64;
  const int o0 = blockIdx.y * 64;
  const int b  = blockIdx.z;

  __shared__ float WmT[32][68];  // [c][o]
  __shared__ float Rs[32][68];   // [c][l]

  const int tid = threadIdx.x;
  const int to  = tid >> 4;
  const int tl  = tid & 15;

  float acc[4][4];
  #pragma unroll
  for (int r = 0; r < 4; ++r)
    #pragma unroll
    for (int j = 0; j < 4; ++j) acc[r][j] = 0.f;

  for (int c0 = 0; c0 < CC; c0 += 32) {
    __syncthreads();
    #pragma unroll
    for (int i = 0; i < 8; ++i) {              // 64x32 Wm tile -> WmT[c][o]
      int flat = tid + 256 * i;
      int o = flat >> 5, c = flat & 31;
      WmT[c][o] = Wm[(size_t)(o0 + o) * CC + c0 + c];
    }
    #pragma unroll
    for (int i = 0; i < 8; ++i) {              // 32x64 R tile
      int flat = tid + 256 * i;
      int c = flat >> 6, l = flat & 63;
      Rs[c][l] = bf2f(rb[((size_t)b * CC + c0 + c) * LL + l0 + l]);
    }
    __syncthreads();
    #pragma unroll 4
    for (int cc = 0; cc < 32; ++cc) {
      f32x4 wv = *(const f32x4*)&WmT[cc][to * 4];
      f32x4 rv = *(const f32x4*)&Rs[cc][tl * 4];
      #pragma unroll
      for (int r = 0; r < 4; ++r)
        #pragma unroll
        for (int j = 0; j < 4; ++j) acc[r][j] += wv[r] * rv[j];
    }
  }

  #pragma unroll
  for (int r = 0; r < 4; ++r) {
    int o = o0 + to * 4 + r;
    float bias = bm[o];
    size_t off = ((size_t)b * CC + o) * LL + l0 + tl * 4;
    f32x4 xv = *reinterpret_cast<const f32x4*>(x + off);
    f32x4 ov;
    #pragma unroll
    for (int j = 0; j < 4; ++j) ov[j] = acc[r][j] + bias + xv[j];
    *reinterpret_cast<f32x4*>(out + off) = ov;
  }
}

// ---------------------------------------------------------------------------
extern "C" void kernel_launch(void* const* d_in, const int* in_sizes, int n_in,
                              void* d_out, int out_size, void* d_ws, size_t ws_size,
                              hipStream_t stream) {
  const float* x     = (const float*)d_in[0];
  const float* Wq    = (const float*)d_in[1];
  const float* bq    = (const float*)d_in[2];
  const float* Wk    = (const float*)d_in[3];
  const float* bk    = (const float*)d_in[4];
  const float* Wv    = (const float*)d_in[5];
  const float* bv    = (const float*)d_in[6];
  const float* scale = (const float*)d_in[7];
  const float* Wm    = (const float*)d_in[8];
  const float* bm    = (const float*)d_in[9];
  float* out = (float*)d_out;

  const size_t nqk = (size_t)BB * NHD * LL * DKD;   // elements per q/k/v buffer
  unsigned short* qn = (unsigned short*)d_ws;
  unsigned short* kn = qn + nqk;
  unsigned short* vb = kn + nqk;
  unsigned short* rb = vb + nqk;                    // [B][NH*DV][L]

  mhsa_proj_kernel<<<dim3(LL / 32, BB * NHD, 3), dim3(256), 0, stream>>>(
      x, Wq, bq, Wk, bk, Wv, bv, scale, qn, kn, vb);
  mhsa_attn_kernel<<<dim3(LL / 16, BB * NHD), dim3(256), 0, stream>>>(qn, kn, vb, rb);
  mhsa_merge_kernel<<<dim3(LL / 64, CC / 64, BB), dim3(256), 0, stream>>>(
      rb, Wm, bm, x, out);
}

// Round 9
// 333.474 us; speedup vs baseline: 1.1933x; 1.0002x over previous
//
#include <hip/hip_runtime.h>

// R9 resubmission (functionally identical to R3; comment-only round tag —
// rounds 3-8 failed on container infrastructure [disk full] before any
// kernel compile/launch).

// Problem constants
#define BB  2
#define CC  256
#define LL  4096   // 64*64 spatial tokens
#define NHD 2
#define DKD 128
#define DVD 128

// Workspace layout (assumes ws_size >= ~34 MB):
//   qn  : bf16 [B][NH][L][DK]   (l2-normalized, * sqrt(scale))
//   kn  : bf16 [B][NH][L][DK]
//   vb  : bf16 [B][NH][DV][L]
//   rb  : bf16 [B][NH*DV][L]    (attention output, pre-merge)

typedef short  short8  __attribute__((ext_vector_type(8)));
typedef float  f32x4   __attribute__((ext_vector_type(4)));
typedef unsigned short ushort4v __attribute__((ext_vector_type(4)));

__device__ __forceinline__ unsigned short f2bf(float f) {
  union { float f; unsigned u; } v; v.f = f;
  unsigned r = v.u + 0x7fffu + ((v.u >> 16) & 1u);   // RNE
  return (unsigned short)(r >> 16);
}
__device__ __forceinline__ float bf2f(unsigned short u) {
  union { unsigned u; float f; } v; v.u = ((unsigned)u) << 16;
  return v.f;
}

// ---------------------------------------------------------------------------
// Kernel 1: QKV 1x1-conv projections (fp32), fused l2-norm for Q/K, bf16 out.
// grid (L/32, B*NH, 3)  block 256.  Tile: full 128 k-rows x 32 l-cols.
// ---------------------------------------------------------------------------
__global__ __launch_bounds__(256) void mhsa_proj_kernel(
    const float* __restrict__ x,
    const float* __restrict__ Wq, const float* __restrict__ bq,
    const float* __restrict__ Wk, const float* __restrict__ bk,
    const float* __restrict__ Wv, const float* __restrict__ bv,
    const float* __restrict__ scale,
    unsigned short* __restrict__ qn,
    unsigned short* __restrict__ kn,
    unsigned short* __restrict__ vb)
{
  const int lt = blockIdx.x * 32;
  const int bh = blockIdx.y;           // b*NH + h
  const int h  = bh % NHD;
  const int b  = bh / NHD;
  const int p  = blockIdx.z;           // 0=Q 1=K 2=V

  const float* W    = (p == 0 ? Wq : (p == 1 ? Wk : Wv)) + (size_t)h * DKD * CC;
  const float* bias = (p == 0 ? bq : (p == 1 ? bk : bv)) + h * DKD;

  __shared__ float WsT[32][132];   // [c][k], transposed W tile (+pad)
  __shared__ float Xs[32][33];     // [c][l]
  __shared__ float red[16][32];
  __shared__ float ninv[32];

  const int tid = threadIdx.x;
  const int tk  = tid >> 4;   // 0..15
  const int tl  = tid & 15;   // 0..15

  float acc[8][2];
  #pragma unroll
  for (int r = 0; r < 8; ++r) { acc[r][0] = 0.f; acc[r][1] = 0.f; }

  const float* xb = x + (size_t)b * CC * LL;

  for (int c0 = 0; c0 < CC; c0 += 32) {
    __syncthreads();
    #pragma unroll
    for (int i = 0; i < 16; ++i) {              // 128x32 W tile -> WsT[c][k]
      int flat = tid + 256 * i;
      int k = flat >> 5, c = flat & 31;
      WsT[c][k] = W[(size_t)k * CC + c0 + c];
    }
    #pragma unroll
    for (int i = 0; i < 4; ++i) {               // 32x32 x tile
      int flat = tid + 256 * i;
      int c = flat >> 5, l = flat & 31;
      Xs[c][l] = xb[(size_t)(c0 + c) * LL + lt + l];
    }
    __syncthreads();
    #pragma unroll 8
    for (int cc = 0; cc < 32; ++cc) {
      float x0 = Xs[cc][tl * 2 + 0];
      float x1 = Xs[cc][tl * 2 + 1];
      f32x4 w0 = *(const f32x4*)&WsT[cc][tk * 8 + 0];
      f32x4 w1 = *(const f32x4*)&WsT[cc][tk * 8 + 4];
      #pragma unroll
      for (int r = 0; r < 4; ++r) {
        acc[r][0]     += w0[r] * x0;  acc[r][1]     += w0[r] * x1;
        acc[r + 4][0] += w1[r] * x0;  acc[r + 4][1] += w1[r] * x1;
      }
    }
  }

  #pragma unroll
  for (int r = 0; r < 8; ++r) {
    float bs = bias[tk * 8 + r];
    acc[r][0] += bs;  acc[r][1] += bs;
  }

  if (p < 2) {
    // column l2-norm over full DK=128
    float s0 = 0.f, s1 = 0.f;
    #pragma unroll
    for (int r = 0; r < 8; ++r) { s0 += acc[r][0] * acc[r][0]; s1 += acc[r][1] * acc[r][1]; }
    __syncthreads();
    red[tk][tl * 2 + 0] = s0;
    red[tk][tl * 2 + 1] = s1;
    __syncthreads();
    if (tid < 32) {
      float s = 0.f;
      #pragma unroll
      for (int i = 0; i < 16; ++i) s += red[i][tid];
      ninv[tid] = sqrtf(scale[h]) / fmaxf(sqrtf(s), 1e-6f);
    }
    __syncthreads();
    unsigned short* out = (p == 0 ? qn : kn) + ((size_t)bh * LL + lt) * DKD;
    float n0 = ninv[tl * 2 + 0], n1 = ninv[tl * 2 + 1];
    #pragma unroll
    for (int j = 0; j < 2; ++j) {
      float nv = j ? n1 : n0;
      short8 pk;
      #pragma unroll
      for (int r = 0; r < 8; ++r) pk[r] = (short)f2bf(acc[r][j] * nv);
      *reinterpret_cast<short8*>(out + (size_t)(tl * 2 + j) * DKD + tk * 8) = pk;
    }
  } else {
    unsigned short* out = vb + (size_t)bh * DVD * LL;
    #pragma unroll
    for (int r = 0; r < 8; ++r) {
      unsigned pk = (unsigned)f2bf(acc[r][0]) | ((unsigned)f2bf(acc[r][1]) << 16);
      *reinterpret_cast<unsigned*>(out + (size_t)(tk * 8 + r) * LL + lt + tl * 2) = pk;
    }
  }
}

// ---------------------------------------------------------------------------
// Kernel 2: flash attention, bf16 MFMA 16x16x32, split-K within block.
// grid (L/16, B*NH) remapped so each XCD's L2 caches exactly one (b,h) K+V.
// block 256 (4 waves); wave w handles keys [w*1024, w*1024+1024).
// STATIC-MAX softmax: after l2norm, S = scale*cos in [-scale, scale] and
// S[q][q] == scale exactly, so M = scale[h] is the EXACT row max. No online
// max, no per-iter cross-lane reduction, no rescale. Row-sum l accumulates
// in-register; one butterfly reduce at the end; combine = plain sum.
// Fragment maps (m89-verified): A row=lane&15, k=(lane>>4)*8+j contiguous;
// B col=lane&15, same k; D col=lane&15, row=(lane>>4)*4+reg.
// ---------------------------------------------------------------------------
#define KCHUNK (LL / 4)   // 1024 keys per wave

__global__ __launch_bounds__(256) void mhsa_attn_kernel(
    const unsigned short* __restrict__ qn,
    const unsigned short* __restrict__ kn,
    const unsigned short* __restrict__ vb,
    const float* __restrict__ scale,
    unsigned short* __restrict__ rb)
{
  // XCD-aware remap: HW round-robins wg-id % 8 over XCDs. Give XCD x the
  // (b,h) = x>>1 and q-half x&1 so each XCD re-reads a 2MB K/V set (L2-fit).
  const int wgid = blockIdx.y * gridDim.x + blockIdx.x;
  const int xcd  = wgid & 7;
  const int slot = wgid >> 3;            // 0..127
  const int bh   = xcd >> 1;             // 0..3
  const int qt   = ((xcd & 1) << 7) + slot;
  const int l0   = qt * 16;

  const int wave = threadIdx.x >> 6;
  const int lane = threadIdx.x & 63;
  const int tid  = threadIdx.x;

  const unsigned short* Q = qn + (size_t)bh * LL * DKD;
  const unsigned short* K = kn + (size_t)bh * LL * DKD;
  const unsigned short* V = vb + (size_t)bh * DVD * LL;
  const float M = scale[bh % NHD];       // exact row max of S

  const int lr = lane & 15;
  const int lc = lane >> 4;

  // per-wave scratch: plds (ushort[16][72], main loop) overlays the bf16
  // partial-result tile (ushort[16][132], combine). Each wave touches only
  // its own region until the single __syncthreads().
  __shared__ unsigned short wscratch[4][16 * 132];   // 16896 B
  __shared__ float lsum_lds[4][16];
  unsigned short* plds = wscratch[wave];             // [16][72]

  short8 qf[4];
  #pragma unroll
  for (int ks = 0; ks < 4; ++ks)
    qf[ks] = *reinterpret_cast<const short8*>(Q + (size_t)(l0 + lr) * DKD + ks * 32 + lc * 8);

  f32x4 racc[8];
  #pragma unroll
  for (int vt = 0; vt < 8; ++vt) racc[vt] = (f32x4){0.f, 0.f, 0.f, 0.f};
  float lsum[4] = {0.f, 0.f, 0.f, 0.f};

  const int mbeg = wave * KCHUNK;
  for (int m0 = mbeg; m0 < mbeg + KCHUNK; m0 += 64) {
    // ---- S tile: 16 q-rows x 64 keys ----
    f32x4 s[4];
    #pragma unroll
    for (int ct = 0; ct < 4; ++ct) {
      f32x4 acc = (f32x4){0.f, 0.f, 0.f, 0.f};
      #pragma unroll
      for (int ks = 0; ks < 4; ++ks) {
        short8 kf = *reinterpret_cast<const short8*>(
            K + (size_t)(m0 + ct * 16 + lr) * DKD + ks * 32 + lc * 8);
        acc = __builtin_amdgcn_mfma_f32_16x16x32_bf16(qf[ks], kf, acc, 0, 0, 0);
      }
      s[ct] = acc;
    }
    // ---- P = exp(S - M), in-register row-sum (no cross-lane ops) ----
    #pragma unroll
    for (int ct = 0; ct < 4; ++ct) {
      #pragma unroll
      for (int r = 0; r < 4; ++r) {
        float pv = __expf(s[ct][r] - M);
        s[ct][r] = pv;
        lsum[r] += pv;
      }
    }
    // ---- P -> LDS (bf16), re-layout D-frag to A-frag (per-wave, no barrier) ----
    #pragma unroll
    for (int ct = 0; ct < 4; ++ct)
      #pragma unroll
      for (int r = 0; r < 4; ++r)
        plds[(lc * 4 + r) * 72 + ct * 16 + lr] = f2bf(s[ct][r]);

    short8 pf[2];
    #pragma unroll
    for (int ks = 0; ks < 2; ++ks)
      pf[ks] = *reinterpret_cast<const short8*>(&plds[lr * 72 + ks * 32 + lc * 8]);

    // ---- PV: racc[vt] += P[16x64] . V^T[64x16] ----
    #pragma unroll
    for (int vt = 0; vt < 8; ++vt) {
      #pragma unroll
      for (int ks = 0; ks < 2; ++ks) {
        short8 vf = *reinterpret_cast<const short8*>(
            V + (size_t)(vt * 16 + lr) * LL + m0 + ks * 32 + lc * 8);
        racc[vt] = __builtin_amdgcn_mfma_f32_16x16x32_bf16(pf[ks], vf, racc[vt], 0, 0, 0);
      }
    }
  }

  // ---- one-time row-sum reduce across the 16 key-lanes ----
  #pragma unroll
  for (int r = 0; r < 4; ++r) {
    float v = lsum[r];
    #pragma unroll
    for (int msk = 8; msk; msk >>= 1) v += __shfl_xor(v, msk, 64);
    lsum[r] = v;
  }

  // ---- dump partials to LDS (bf16; overlays plds — within-wave order ok) ----
  #pragma unroll
  for (int vt = 0; vt < 8; ++vt)
    #pragma unroll
    for (int r = 0; r < 4; ++r)
      wscratch[wave][(lc * 4 + r) * 132 + vt * 16 + lr] = f2bf(racc[vt][r]);
  if (lr == 0) {
    #pragma unroll
    for (int r = 0; r < 4; ++r) lsum_lds[wave][lc * 4 + r] = lsum[r];
  }
  __syncthreads();

  // ---- combine across the 4 waves: plain sums (shared static max) ----
  const int q   = tid & 15;        // q-row within tile
  const int vb0 = tid >> 4;        // 0..15
  float Ls = lsum_lds[0][q] + lsum_lds[1][q] + lsum_lds[2][q] + lsum_lds[3][q];
  float invL = 1.f / Ls;
  unsigned short* Rb = rb + (size_t)bh * DVD * LL;
  #pragma unroll
  for (int it = 0; it < 8; ++it) {
    int v = it * 16 + vb0;
    float sacc = bf2f(wscratch[0][q * 132 + v]) + bf2f(wscratch[1][q * 132 + v])
               + bf2f(wscratch[2][q * 132 + v]) + bf2f(wscratch[3][q * 132 + v]);
    Rb[(size_t)v * LL + l0 + q] = f2bf(sacc * invL);
  }
}

// ---------------------------------------------------------------------------
// Kernel 3: merge 1x1 conv + bias + residual (fp32).
// grid (L/64, C/64, B)  block 256; thread computes 4x4 outputs.
// ---------------------------------------------------------------------------
__global__ __launch_bounds__(256) void mhsa_merge_kernel(
    const unsigned short* __restrict__ rb,
    const float* __restrict__ Wm,
    const float* __restrict__ bm,
    const float* __restrict__ x,
    float* __restrict__ out)
{
  const int l0 = blockIdx.x * 64;
  const int o0 = blockIdx.y * 64;
  const int b  = blockIdx.z;

  __shared__ float WmT[32][68];  // [c][o]
  __shared__ float Rs[32][68];   // [c][l]

  const int tid = threadIdx.x;
  const int to  = tid >> 4;
  const int tl  = tid & 15;

  float acc[4][4];
  #pragma unroll
  for (int r = 0; r < 4; ++r)
    #pragma unroll
    for (int j = 0; j < 4; ++j) acc[r][j] = 0.f;

  for (int c0 = 0; c0 < CC; c0 += 32) {
    __syncthreads();
    #pragma unroll
    for (int i = 0; i < 8; ++i) {              // 64x32 Wm tile -> WmT[c][o]
      int flat = tid + 256 * i;
      int o = flat >> 5, c = flat & 31;
      WmT[c][o] = Wm[(size_t)(o0 + o) * CC + c0 + c];
    }
    #pragma unroll
    for (int i = 0; i < 8; ++i) {              // 32x64 R tile
      int flat = tid + 256 * i;
      int c = flat >> 6, l = flat & 63;
      Rs[c][l] = bf2f(rb[((size_t)b * CC + c0 + c) * LL + l0 + l]);
    }
    __syncthreads();
    #pragma unroll 4
    for (int cc = 0; cc < 32; ++cc) {
      f32x4 wv = *(const f32x4*)&WmT[cc][to * 4];
      f32x4 rv = *(const f32x4*)&Rs[cc][tl * 4];
      #pragma unroll
      for (int r = 0; r < 4; ++r)
        #pragma unroll
        for (int j = 0; j < 4; ++j) acc[r][j] += wv[r] * rv[j];
    }
  }

  #pragma unroll
  for (int r = 0; r < 4; ++r) {
    int o = o0 + to * 4 + r;
    float bias = bm[o];
    size_t off = ((size_t)b * CC + o) * LL + l0 + tl * 4;
    f32x4 xv = *reinterpret_cast<const f32x4*>(x + off);
    f32x4 ov;
    #pragma unroll
    for (int j = 0; j < 4; ++j) ov[j] = acc[r][j] + bias + xv[j];
    *reinterpret_cast<f32x4*>(out + off) = ov;
  }
}

// ---------------------------------------------------------------------------
extern "C" void kernel_launch(void* const* d_in, const int* in_sizes, int n_in,
                              void* d_out, int out_size, void* d_ws, size_t ws_size,
                              hipStream_t stream) {
  const float* x     = (const float*)d_in[0];
  const float* Wq    = (const float*)d_in[1];
  const float* bq    = (const float*)d_in[2];
  const float* Wk    = (const float*)d_in[3];
  const float* bk    = (const float*)d_in[4];
  const float* Wv    = (const float*)d_in[5];
  const float* bv    = (const float*)d_in[6];
  const float* scale = (const float*)d_in[7];
  const float* Wm    = (const float*)d_in[8];
  const float* bm    = (const float*)d_in[9];
  float* out = (float*)d_out;

  const size_t nqk = (size_t)BB * NHD * LL * DKD;   // elements per q/k/v buffer
  unsigned short* qn = (unsigned short*)d_ws;
  unsigned short* kn = qn + nqk;
  unsigned short* vb = kn + nqk;
  unsigned short* rb = vb + nqk;                    // [B][NH*DV][L]

  mhsa_proj_kernel<<<dim3(LL / 32, BB * NHD, 3), dim3(256), 0, stream>>>(
      x, Wq, bq, Wk, bk, Wv, bv, scale, qn, kn, vb);
  mhsa_attn_kernel<<<dim3(LL / 16, BB * NHD), dim3(256), 0, stream>>>(qn, kn, vb, scale, rb);
  mhsa_merge_kernel<<<dim3(LL / 64, CC / 64, BB), dim3(256), 0, stream>>>(
      rb, Wm, bm, x, out);
}

// Round 10
// 215.970 us; speedup vs baseline: 1.8426x; 1.5441x over previous
//
#include <hip/hip_runtime.h>

// R10: attention restructured — 64 q-rows/block, K+V LDS-staged (global_load_lds
// width 16, double-buffered, XOR-swizzled via pre-swizzled global source).
// Diagnosis: R2/R9 both ~600Kcy with all pipes idle -> bound by scattered
// per-thread fragment loads (16 x 64B lines per wave-instr) through L2.

// Problem constants
#define BB  2
#define CC  256
#define LL  4096   // 64*64 spatial tokens
#define NHD 2
#define DKD 128
#define DVD 128

#define QBLK  64
#define KVBLK 64
#define NKT   (LL / KVBLK)   // 64 key tiles

typedef short  short8  __attribute__((ext_vector_type(8)));
typedef float  f32x4   __attribute__((ext_vector_type(4)));
typedef unsigned short ushort4v __attribute__((ext_vector_type(4)));

__device__ __forceinline__ unsigned short f2bf(float f) {
  union { float f; unsigned u; } v; v.f = f;
  unsigned r = v.u + 0x7fffu + ((v.u >> 16) & 1u);   // RNE
  return (unsigned short)(r >> 16);
}
__device__ __forceinline__ float bf2f(unsigned short u) {
  union { unsigned u; float f; } v; v.u = ((unsigned)u) << 16;
  return v.f;
}
__device__ __forceinline__ void glds16(const unsigned short* g, unsigned short* l) {
  // async global->LDS, 16B per lane; LDS dest = wave-uniform base + lane*16
  __builtin_amdgcn_global_load_lds(
      (const __attribute__((address_space(1))) void*)g,
      (__attribute__((address_space(3))) void*)l, 16, 0, 0);
}

// ---------------------------------------------------------------------------
// Kernel 1: QKV 1x1-conv projections (fp32), fused l2-norm for Q/K, bf16 out.
// grid (L/32, B*NH, 3)  block 256.  (unchanged from R9 — passed)
// ---------------------------------------------------------------------------
__global__ __launch_bounds__(256) void mhsa_proj_kernel(
    const float* __restrict__ x,
    const float* __restrict__ Wq, const float* __restrict__ bq,
    const float* __restrict__ Wk, const float* __restrict__ bk,
    const float* __restrict__ Wv, const float* __restrict__ bv,
    const float* __restrict__ scale,
    unsigned short* __restrict__ qn,
    unsigned short* __restrict__ kn,
    unsigned short* __restrict__ vb)
{
  const int lt = blockIdx.x * 32;
  const int bh = blockIdx.y;           // b*NH + h
  const int h  = bh % NHD;
  const int b  = bh / NHD;
  const int p  = blockIdx.z;           // 0=Q 1=K 2=V

  const float* W    = (p == 0 ? Wq : (p == 1 ? Wk : Wv)) + (size_t)h * DKD * CC;
  const float* bias = (p == 0 ? bq : (p == 1 ? bk : bv)) + h * DKD;

  __shared__ float WsT[32][132];
  __shared__ float Xs[32][33];
  __shared__ float red[16][32];
  __shared__ float ninv[32];

  const int tid = threadIdx.x;
  const int tk  = tid >> 4;
  const int tl  = tid & 15;

  float acc[8][2];
  #pragma unroll
  for (int r = 0; r < 8; ++r) { acc[r][0] = 0.f; acc[r][1] = 0.f; }

  const float* xb = x + (size_t)b * CC * LL;

  for (int c0 = 0; c0 < CC; c0 += 32) {
    __syncthreads();
    #pragma unroll
    for (int i = 0; i < 16; ++i) {
      int flat = tid + 256 * i;
      int k = flat >> 5, c = flat & 31;
      WsT[c][k] = W[(size_t)k * CC + c0 + c];
    }
    #pragma unroll
    for (int i = 0; i < 4; ++i) {
      int flat = tid + 256 * i;
      int c = flat >> 5, l = flat & 31;
      Xs[c][l] = xb[(size_t)(c0 + c) * LL + lt + l];
    }
    __syncthreads();
    #pragma unroll 8
    for (int cc = 0; cc < 32; ++cc) {
      float x0 = Xs[cc][tl * 2 + 0];
      float x1 = Xs[cc][tl * 2 + 1];
      f32x4 w0 = *(const f32x4*)&WsT[cc][tk * 8 + 0];
      f32x4 w1 = *(const f32x4*)&WsT[cc][tk * 8 + 4];
      #pragma unroll
      for (int r = 0; r < 4; ++r) {
        acc[r][0]     += w0[r] * x0;  acc[r][1]     += w0[r] * x1;
        acc[r + 4][0] += w1[r] * x0;  acc[r + 4][1] += w1[r] * x1;
      }
    }
  }

  #pragma unroll
  for (int r = 0; r < 8; ++r) {
    float bs = bias[tk * 8 + r];
    acc[r][0] += bs;  acc[r][1] += bs;
  }

  if (p < 2) {
    float s0 = 0.f, s1 = 0.f;
    #pragma unroll
    for (int r = 0; r < 8; ++r) { s0 += acc[r][0] * acc[r][0]; s1 += acc[r][1] * acc[r][1]; }
    __syncthreads();
    red[tk][tl * 2 + 0] = s0;
    red[tk][tl * 2 + 1] = s1;
    __syncthreads();
    if (tid < 32) {
      float s = 0.f;
      #pragma unroll
      for (int i = 0; i < 16; ++i) s += red[i][tid];
      ninv[tid] = sqrtf(scale[h]) / fmaxf(sqrtf(s), 1e-6f);
    }
    __syncthreads();
    unsigned short* out = (p == 0 ? qn : kn) + ((size_t)bh * LL + lt) * DKD;
    float n0 = ninv[tl * 2 + 0], n1 = ninv[tl * 2 + 1];
    #pragma unroll
    for (int j = 0; j < 2; ++j) {
      float nv = j ? n1 : n0;
      short8 pk;
      #pragma unroll
      for (int r = 0; r < 8; ++r) pk[r] = (short)f2bf(acc[r][j] * nv);
      *reinterpret_cast<short8*>(out + (size_t)(tl * 2 + j) * DKD + tk * 8) = pk;
    }
  } else {
    unsigned short* out = vb + (size_t)bh * DVD * LL;
    #pragma unroll
    for (int r = 0; r < 8; ++r) {
      unsigned pk = (unsigned)f2bf(acc[r][0]) | ((unsigned)f2bf(acc[r][1]) << 16);
      *reinterpret_cast<unsigned*>(out + (size_t)(tk * 8 + r) * LL + lt + tl * 2) = pk;
    }
  }
}

// ---------------------------------------------------------------------------
// Kernel 2: flash attention, 64 q-rows/block (4 waves x 16), LDS-staged K/V.
// grid (L/64, B*NH) = 256 blocks (1/CU), remapped: each XCD pair-shares one
// (b,h)'s 2MB K/V in its L2. Per 64-key tile: stage K[64][128] and V[128][64]
// (bf16) via 32 contiguous global_load_lds dwordx4 (8/wave), double-buffered.
// Bank conflicts on row-major tiles killed by chunk-XOR swizzle applied on
// BOTH the global source (pre-swizzle) and the LDS read (G21 involution):
//   K: slot(r,c') holds chunk c'^(r&7), c' in [0,16)  [256B rows]
//   V: slot(v,c') holds chunk c'^(v&7), c' in [0,8)   [128B rows]
// STATIC-MAX softmax (S[q][q]==scale exactly after l2norm): M = scale[h].
// ---------------------------------------------------------------------------
__global__ __launch_bounds__(256) void mhsa_attn_kernel(
    const unsigned short* __restrict__ qn,
    const unsigned short* __restrict__ kn,
    const unsigned short* __restrict__ vb,
    const float* __restrict__ scale,
    unsigned short* __restrict__ rb)
{
  const int wgid = blockIdx.y * gridDim.x + blockIdx.x;  // 0..255
  const int xcd  = wgid & 7;
  const int slot = wgid >> 3;            // 0..31
  const int bh   = xcd >> 1;             // 0..3
  const int qt   = ((xcd & 1) << 5) + slot;   // 0..63
  const int l0   = qt * QBLK;

  const int wave = threadIdx.x >> 6;
  const int lane = threadIdx.x & 63;
  const int lr   = lane & 15;
  const int lc   = lane >> 4;

  const unsigned short* Q = qn + (size_t)bh * LL * DKD;
  const unsigned short* K = kn + (size_t)bh * LL * DKD;
  const unsigned short* V = vb + (size_t)bh * DVD * LL;
  const float M = scale[bh & 1];         // exact row max of S

  __shared__ unsigned short Ks[2][KVBLK * DKD];   // 2 x 16KB
  __shared__ unsigned short Vs[2][DVD * KVBLK];   // 2 x 16KB
  __shared__ unsigned short plds[4][16 * 72];     // per-wave P tile (+pad)
  unsigned short* myp = plds[wave];

  // ---- Q fragments (once) ----
  const int l0w = l0 + wave * 16;
  short8 qf[4];
  #pragma unroll
  for (int ks = 0; ks < 4; ++ks)
    qf[ks] = *reinterpret_cast<const short8*>(Q + (size_t)(l0w + lr) * DKD + ks * 32 + lc * 8);

  // ---- per-lane staging offsets (ushort units), instr i = wave*4+j ----
  int offK[4], offV[4], ldsOff[4];
  #pragma unroll
  for (int j = 0; j < 4; ++j) {
    int ii = wave * 4 + j;                    // 0..15
    int rK = ii * 4 + (lane >> 4);            // K row 0..63
    int cK = (lane & 15) ^ (rK & 7);          // pre-swizzled 16B chunk
    offK[j] = rK * DKD + cK * 8;
    int vV = ii * 8 + (lane >> 3);            // V row 0..127
    int cV = (lane & 7) ^ (lane >> 3);        // (vV&7) == lane>>3
    offV[j] = vV * LL + cV * 8;
    ldsOff[j] = ii * 512;                     // 1KB per instr
  }

  f32x4 racc[8];
  #pragma unroll
  for (int vt = 0; vt < 8; ++vt) racc[vt] = (f32x4){0.f, 0.f, 0.f, 0.f};
  float lsum[4] = {0.f, 0.f, 0.f, 0.f};

  // ---- prologue: stage tile 0 into buf 0 ----
  #pragma unroll
  for (int j = 0; j < 4; ++j) {
    glds16(K + offK[j], &Ks[0][ldsOff[j]]);
    glds16(V + offV[j], &Vs[0][ldsOff[j]]);
  }
  __syncthreads();

  const int sw = lr & 7;
  int buf = 0;
  for (int t = 0; t < NKT; ++t) {
    // ---- issue next-tile staging (async, overlaps compute) ----
    if (t + 1 < NKT) {
      int m1 = (t + 1) * KVBLK;
      #pragma unroll
      for (int j = 0; j < 4; ++j) {
        glds16(K + (size_t)m1 * DKD + offK[j], &Ks[buf ^ 1][ldsOff[j]]);
        glds16(V + m1 + offV[j],               &Vs[buf ^ 1][ldsOff[j]]);
      }
    }

    // ---- S tile: 16 q-rows x 64 keys (K from LDS, swizzled read) ----
    f32x4 s[4];
    #pragma unroll
    for (int ct = 0; ct < 4; ++ct) {
      f32x4 acc = (f32x4){0.f, 0.f, 0.f, 0.f};
      #pragma unroll
      for (int ks = 0; ks < 4; ++ks) {
        short8 kf = *reinterpret_cast<const short8*>(
            &Ks[buf][(ct * 16 + lr) * DKD + ((ks * 4 + lc) ^ sw) * 8]);
        acc = __builtin_amdgcn_mfma_f32_16x16x32_bf16(qf[ks], kf, acc, 0, 0, 0);
      }
      s[ct] = acc;
    }

    // ---- P = exp(S - M), in-register row-sum ----
    #pragma unroll
    for (int ct = 0; ct < 4; ++ct) {
      #pragma unroll
      for (int r = 0; r < 4; ++r) {
        float pv = __expf(s[ct][r] - M);
        s[ct][r] = pv;
        lsum[r] += pv;
      }
    }

    // ---- P -> per-wave LDS (bf16), D-frag -> A-frag re-layout ----
    #pragma unroll
    for (int ct = 0; ct < 4; ++ct)
      #pragma unroll
      for (int r = 0; r < 4; ++r)
        myp[(lc * 4 + r) * 72 + ct * 16 + lr] = f2bf(s[ct][r]);

    short8 pf[2];
    #pragma unroll
    for (int ks = 0; ks < 2; ++ks)
      pf[ks] = *reinterpret_cast<const short8*>(&myp[lr * 72 + ks * 32 + lc * 8]);

    // ---- PV: racc[vt] += P[16x64] . V^T[64x16] (V from LDS, swizzled) ----
    #pragma unroll
    for (int vt = 0; vt < 8; ++vt) {
      #pragma unroll
      for (int ks = 0; ks < 2; ++ks) {
        short8 vf = *reinterpret_cast<const short8*>(
            &Vs[buf][(vt * 16 + lr) * KVBLK + ((ks * 4 + lc) ^ sw) * 8]);
        racc[vt] = __builtin_amdgcn_mfma_f32_16x16x32_bf16(pf[ks], vf, racc[vt], 0, 0, 0);
      }
    }

    __syncthreads();   // drains staging (vmcnt0) + all waves done with buf
    buf ^= 1;
  }

  // ---- row-sum reduce across the 16 key-lanes ----
  #pragma unroll
  for (int r = 0; r < 4; ++r) {
    float v = lsum[r];
    #pragma unroll
    for (int msk = 8; msk; msk >>= 1) v += __shfl_xor(v, msk, 64);
    lsum[r] = v;
  }
  float inv[4];
  #pragma unroll
  for (int r = 0; r < 4; ++r) inv[r] = 1.f / lsum[r];

  // ---- write rb[bh][v][l] (bf16), 8B packed per vt ----
  unsigned short* Rb = rb + (size_t)bh * DVD * LL;
  #pragma unroll
  for (int vt = 0; vt < 8; ++vt) {
    ushort4v pk;
    #pragma unroll
    for (int r = 0; r < 4; ++r) pk[r] = f2bf(racc[vt][r] * inv[r]);
    *reinterpret_cast<ushort4v*>(Rb + (size_t)(vt * 16 + lr) * LL + l0w + lc * 4) = pk;
  }
}

// ---------------------------------------------------------------------------
// Kernel 3: merge 1x1 conv + bias + residual (fp32). (unchanged from R9)
// ---------------------------------------------------------------------------
__global__ __launch_bounds__(256) void mhsa_merge_kernel(
    const unsigned short* __restrict__ rb,
    const float* __restrict__ Wm,
    const float* __restrict__ bm,
    const float* __restrict__ x,
    float* __restrict__ out)
{
  const int l0 = blockIdx.x * 64;
  const int o0 = blockIdx.y * 64;
  const int b  = blockIdx.z;

  __shared__ float WmT[32][68];
  __shared__ float Rs[32][68];

  const int tid = threadIdx.x;
  const int to  = tid >> 4;
  const int tl  = tid & 15;

  float acc[4][4];
  #pragma unroll
  for (int r = 0; r < 4; ++r)
    #pragma unroll
    for (int j = 0; j < 4; ++j) acc[r][j] = 0.f;

  for (int c0 = 0; c0 < CC; c0 += 32) {
    __syncthreads();
    #pragma unroll
    for (int i = 0; i < 8; ++i) {
      int flat = tid + 256 * i;
      int o = flat >> 5, c = flat & 31;
      WmT[c][o] = Wm[(size_t)(o0 + o) * CC + c0 + c];
    }
    #pragma unroll
    for (int i = 0; i < 8; ++i) {
      int flat = tid + 256 * i;
      int c = flat >> 6, l = flat & 63;
      Rs[c][l] = bf2f(rb[((size_t)b * CC + c0 + c) * LL + l0 + l]);
    }
    __syncthreads();
    #pragma unroll 4
    for (int cc = 0; cc < 32; ++cc) {
      f32x4 wv = *(const f32x4*)&WmT[cc][to * 4];
      f32x4 rv = *(const f32x4*)&Rs[cc][tl * 4];
      #pragma unroll
      for (int r = 0; r < 4; ++r)
        #pragma unroll
        for (int j = 0; j < 4; ++j) acc[r][j] += wv[r] * rv[j];
    }
  }

  #pragma unroll
  for (int r = 0; r < 4; ++r) {
    int o = o0 + to * 4 + r;
    float bias = bm[o];
    size_t off = ((size_t)b * CC + o) * LL + l0 + tl * 4;
    f32x4 xv = *reinterpret_cast<const f32x4*>(x + off);
    f32x4 ov;
    #pragma unroll
    for (int j = 0; j < 4; ++j) ov[j] = acc[r][j] + bias + xv[j];
    *reinterpret_cast<f32x4*>(out + off) = ov;
  }
}

// ---------------------------------------------------------------------------
extern "C" void kernel_launch(void* const* d_in, const int* in_sizes, int n_in,
                              void* d_out, int out_size, void* d_ws, size_t ws_size,
                              hipStream_t stream) {
  const float* x     = (const float*)d_in[0];
  const float* Wq    = (const float*)d_in[1];
  const float* bq    = (const float*)d_in[2];
  const float* Wk    = (const float*)d_in[3];
  const float* bk    = (const float*)d_in[4];
  const float* Wv    = (const float*)d_in[5];
  const float* bv    = (const float*)d_in[6];
  const float* scale = (const float*)d_in[7];
  const float* Wm    = (const float*)d_in[8];
  const float* bm    = (const float*)d_in[9];
  float* out = (float*)d_out;

  const size_t nqk = (size_t)BB * NHD * LL * DKD;   // elements per q/k/v buffer
  unsigned short* qn = (unsigned short*)d_ws;
  unsigned short* kn = qn + nqk;
  unsigned short* vb = kn + nqk;
  unsigned short* rb = vb + nqk;                    // [B][NH*DV][L]

  mhsa_proj_kernel<<<dim3(LL / 32, BB * NHD, 3), dim3(256), 0, stream>>>(
      x, Wq, bq, Wk, bk, Wv, bv, scale, qn, kn, vb);
  mhsa_attn_kernel<<<dim3(LL / QBLK, BB * NHD), dim3(256), 0, stream>>>(
      qn, kn, vb, scale, rb);
  mhsa_merge_kernel<<<dim3(LL / 64, CC / 64, BB), dim3(256), 0, stream>>>(
      rb, Wm, bm, x, out);
}

// Round 11
// 215.968 us; speedup vs baseline: 1.8426x; 1.0000x over previous
//
#include <hip/hip_runtime.h>

// R10: attention restructured — 64 q-rows/block, K+V LDS-staged (global_load_lds
// width 16, double-buffered, XOR-swizzled via pre-swizzled global source).
// Diagnosis: R2/R9 both ~600Kcy with all pipes idle -> bound by scattered
// per-thread fragment loads (16 x 64B lines per wave-instr) through L2.

// Problem constants
#define BB  2
#define CC  256
#define LL  4096   // 64*64 spatial tokens
#define NHD 2
#define DKD 128
#define DVD 128

#define QBLK  64
#define KVBLK 64
#define NKT   (LL / KVBLK)   // 64 key tiles

typedef short  short8  __attribute__((ext_vector_type(8)));
typedef float  f32x4   __attribute__((ext_vector_type(4)));
typedef unsigned short ushort4v __attribute__((ext_vector_type(4)));

__device__ __forceinline__ unsigned short f2bf(float f) {
  union { float f; unsigned u; } v; v.f = f;
  unsigned r = v.u + 0x7fffu + ((v.u >> 16) & 1u);   // RNE
  return (unsigned short)(r >> 16);
}
__device__ __forceinline__ float bf2f(unsigned short u) {
  union { unsigned u; float f; } v; v.u = ((unsigned)u) << 16;
  return v.f;
}
__device__ __forceinline__ void glds16(const unsigned short* g, unsigned short* l) {
  // async global->LDS, 16B per lane; LDS dest = wave-uniform base + lane*16
  __builtin_amdgcn_global_load_lds(
      (const __attribute__((address_space(1))) void*)g,
      (__attribute__((address_space(3))) void*)l, 16, 0, 0);
}

// ---------------------------------------------------------------------------
// Kernel 1: QKV 1x1-conv projections (fp32), fused l2-norm for Q/K, bf16 out.
// grid (L/32, B*NH, 3)  block 256.  (unchanged from R9 — passed)
// ---------------------------------------------------------------------------
__global__ __launch_bounds__(256) void mhsa_proj_kernel(
    const float* __restrict__ x,
    const float* __restrict__ Wq, const float* __restrict__ bq,
    const float* __restrict__ Wk, const float* __restrict__ bk,
    const float* __restrict__ Wv, const float* __restrict__ bv,
    const float* __restrict__ scale,
    unsigned short* __restrict__ qn,
    unsigned short* __restrict__ kn,
    unsigned short* __restrict__ vb)
{
  const int lt = blockIdx.x * 32;
  const int bh = blockIdx.y;           // b*NH + h
  const int h  = bh % NHD;
  const int b  = bh / NHD;
  const int p  = blockIdx.z;           // 0=Q 1=K 2=V

  const float* W    = (p == 0 ? Wq : (p == 1 ? Wk : Wv)) + (size_t)h * DKD * CC;
  const float* bias = (p == 0 ? bq : (p == 1 ? bk : bv)) + h * DKD;

  __shared__ float WsT[32][132];
  __shared__ float Xs[32][33];
  __shared__ float red[16][32];
  __shared__ float ninv[32];

  const int tid = threadIdx.x;
  const int tk  = tid >> 4;
  const int tl  = tid & 15;

  float acc[8][2];
  #pragma unroll
  for (int r = 0; r < 8; ++r) { acc[r][0] = 0.f; acc[r][1] = 0.f; }

  const float* xb = x + (size_t)b * CC * LL;

  for (int c0 = 0; c0 < CC; c0 += 32) {
    __syncthreads();
    #pragma unroll
    for (int i = 0; i < 16; ++i) {
      int flat = tid + 256 * i;
      int k = flat >> 5, c = flat & 31;
      WsT[c][k] = W[(size_t)k * CC + c0 + c];
    }
    #pragma unroll
    for (int i = 0; i < 4; ++i) {
      int flat = tid + 256 * i;
      int c = flat >> 5, l = flat & 31;
      Xs[c][l] = xb[(size_t)(c0 + c) * LL + lt + l];
    }
    __syncthreads();
    #pragma unroll 8
    for (int cc = 0; cc < 32; ++cc) {
      float x0 = Xs[cc][tl * 2 + 0];
      float x1 = Xs[cc][tl * 2 + 1];
      f32x4 w0 = *(const f32x4*)&WsT[cc][tk * 8 + 0];
      f32x4 w1 = *(const f32x4*)&WsT[cc][tk * 8 + 4];
      #pragma unroll
      for (int r = 0; r < 4; ++r) {
        acc[r][0]     += w0[r] * x0;  acc[r][1]     += w0[r] * x1;
        acc[r + 4][0] += w1[r] * x0;  acc[r + 4][1] += w1[r] * x1;
      }
    }
  }

  #pragma unroll
  for (int r = 0; r < 8; ++r) {
    float bs = bias[tk * 8 + r];
    acc[r][0] += bs;  acc[r][1] += bs;
  }

  if (p < 2) {
    float s0 = 0.f, s1 = 0.f;
    #pragma unroll
    for (int r = 0; r < 8; ++r) { s0 += acc[r][0] * acc[r][0]; s1 += acc[r][1] * acc[r][1]; }
    __syncthreads();
    red[tk][tl * 2 + 0] = s0;
    red[tk][tl * 2 + 1] = s1;
    __syncthreads();
    if (tid < 32) {
      float s = 0.f;
      #pragma unroll
      for (int i = 0; i < 16; ++i) s += red[i][tid];
      ninv[tid] = sqrtf(scale[h]) / fmaxf(sqrtf(s), 1e-6f);
    }
    __syncthreads();
    unsigned short* out = (p == 0 ? qn : kn) + ((size_t)bh * LL + lt) * DKD;
    float n0 = ninv[tl * 2 + 0], n1 = ninv[tl * 2 + 1];
    #pragma unroll
    for (int j = 0; j < 2; ++j) {
      float nv = j ? n1 : n0;
      short8 pk;
      #pragma unroll
      for (int r = 0; r < 8; ++r) pk[r] = (short)f2bf(acc[r][j] * nv);
      *reinterpret_cast<short8*>(out + (size_t)(tl * 2 + j) * DKD + tk * 8) = pk;
    }
  } else {
    unsigned short* out = vb + (size_t)bh * DVD * LL;
    #pragma unroll
    for (int r = 0; r < 8; ++r) {
      unsigned pk = (unsigned)f2bf(acc[r][0]) | ((unsigned)f2bf(acc[r][1]) << 16);
      *reinterpret_cast<unsigned*>(out + (size_t)(tk * 8 + r) * LL + lt + tl * 2) = pk;
    }
  }
}

// ---------------------------------------------------------------------------
// Kernel 2: flash attention, 64 q-rows/block (4 waves x 16), LDS-staged K/V.
// grid (L/64, B*NH) = 256 blocks (1/CU), remapped: each XCD pair-shares one
// (b,h)'s 2MB K/V in its L2. Per 64-key tile: stage K[64][128] and V[128][64]
// (bf16) via 32 contiguous global_load_lds dwordx4 (8/wave), double-buffered.
// Bank conflicts on row-major tiles killed by chunk-XOR swizzle applied on
// BOTH the global source (pre-swizzle) and the LDS read (G21 involution):
//   K: slot(r,c') holds chunk c'^(r&7), c' in [0,16)  [256B rows]
//   V: slot(v,c') holds chunk c'^(v&7), c' in [0,8)   [128B rows]
// STATIC-MAX softmax (S[q][q]==scale exactly after l2norm): M = scale[h].
// ---------------------------------------------------------------------------
__global__ __launch_bounds__(256) void mhsa_attn_kernel(
    const unsigned short* __restrict__ qn,
    const unsigned short* __restrict__ kn,
    const unsigned short* __restrict__ vb,
    const float* __restrict__ scale,
    unsigned short* __restrict__ rb)
{
  const int wgid = blockIdx.y * gridDim.x + blockIdx.x;  // 0..255
  const int xcd  = wgid & 7;
  const int slot = wgid >> 3;            // 0..31
  const int bh   = xcd >> 1;             // 0..3
  const int qt   = ((xcd & 1) << 5) + slot;   // 0..63
  const int l0   = qt * QBLK;

  const int wave = threadIdx.x >> 6;
  const int lane = threadIdx.x & 63;
  const int lr   = lane & 15;
  const int lc   = lane >> 4;

  const unsigned short* Q = qn + (size_t)bh * LL * DKD;
  const unsigned short* K = kn + (size_t)bh * LL * DKD;
  const unsigned short* V = vb + (size_t)bh * DVD * LL;
  const float M = scale[bh & 1];         // exact row max of S

  __shared__ unsigned short Ks[2][KVBLK * DKD];   // 2 x 16KB
  __shared__ unsigned short Vs[2][DVD * KVBLK];   // 2 x 16KB
  __shared__ unsigned short plds[4][16 * 72];     // per-wave P tile (+pad)
  unsigned short* myp = plds[wave];

  // ---- Q fragments (once) ----
  const int l0w = l0 + wave * 16;
  short8 qf[4];
  #pragma unroll
  for (int ks = 0; ks < 4; ++ks)
    qf[ks] = *reinterpret_cast<const short8*>(Q + (size_t)(l0w + lr) * DKD + ks * 32 + lc * 8);

  // ---- per-lane staging offsets (ushort units), instr i = wave*4+j ----
  int offK[4], offV[4], ldsOff[4];
  #pragma unroll
  for (int j = 0; j < 4; ++j) {
    int ii = wave * 4 + j;                    // 0..15
    int rK = ii * 4 + (lane >> 4);            // K row 0..63
    int cK = (lane & 15) ^ (rK & 7);          // pre-swizzled 16B chunk
    offK[j] = rK * DKD + cK * 8;
    int vV = ii * 8 + (lane >> 3);            // V row 0..127
    int cV = (lane & 7) ^ (lane >> 3);        // (vV&7) == lane>>3
    offV[j] = vV * LL + cV * 8;
    ldsOff[j] = ii * 512;                     // 1KB per instr
  }

  f32x4 racc[8];
  #pragma unroll
  for (int vt = 0; vt < 8; ++vt) racc[vt] = (f32x4){0.f, 0.f, 0.f, 0.f};
  float lsum[4] = {0.f, 0.f, 0.f, 0.f};

  // ---- prologue: stage tile 0 into buf 0 ----
  #pragma unroll
  for (int j = 0; j < 4; ++j) {
    glds16(K + offK[j], &Ks[0][ldsOff[j]]);
    glds16(V + offV[j], &Vs[0][ldsOff[j]]);
  }
  __syncthreads();

  const int sw = lr & 7;
  int buf = 0;
  for (int t = 0; t < NKT; ++t) {
    // ---- issue next-tile staging (async, overlaps compute) ----
    if (t + 1 < NKT) {
      int m1 = (t + 1) * KVBLK;
      #pragma unroll
      for (int j = 0; j < 4; ++j) {
        glds16(K + (size_t)m1 * DKD + offK[j], &Ks[buf ^ 1][ldsOff[j]]);
        glds16(V + m1 + offV[j],               &Vs[buf ^ 1][ldsOff[j]]);
      }
    }

    // ---- S tile: 16 q-rows x 64 keys (K from LDS, swizzled read) ----
    f32x4 s[4];
    #pragma unroll
    for (int ct = 0; ct < 4; ++ct) {
      f32x4 acc = (f32x4){0.f, 0.f, 0.f, 0.f};
      #pragma unroll
      for (int ks = 0; ks < 4; ++ks) {
        short8 kf = *reinterpret_cast<const short8*>(
            &Ks[buf][(ct * 16 + lr) * DKD + ((ks * 4 + lc) ^ sw) * 8]);
        acc = __builtin_amdgcn_mfma_f32_16x16x32_bf16(qf[ks], kf, acc, 0, 0, 0);
      }
      s[ct] = acc;
    }

    // ---- P = exp(S - M), in-register row-sum ----
    #pragma unroll
    for (int ct = 0; ct < 4; ++ct) {
      #pragma unroll
      for (int r = 0; r < 4; ++r) {
        float pv = __expf(s[ct][r] - M);
        s[ct][r] = pv;
        lsum[r] += pv;
      }
    }

    // ---- P -> per-wave LDS (bf16), D-frag -> A-frag re-layout ----
    #pragma unroll
    for (int ct = 0; ct < 4; ++ct)
      #pragma unroll
      for (int r = 0; r < 4; ++r)
        myp[(lc * 4 + r) * 72 + ct * 16 + lr] = f2bf(s[ct][r]);

    short8 pf[2];
    #pragma unroll
    for (int ks = 0; ks < 2; ++ks)
      pf[ks] = *reinterpret_cast<const short8*>(&myp[lr * 72 + ks * 32 + lc * 8]);

    // ---- PV: racc[vt] += P[16x64] . V^T[64x16] (V from LDS, swizzled) ----
    #pragma unroll
    for (int vt = 0; vt < 8; ++vt) {
      #pragma unroll
      for (int ks = 0; ks < 2; ++ks) {
        short8 vf = *reinterpret_cast<const short8*>(
            &Vs[buf][(vt * 16 + lr) * KVBLK + ((ks * 4 + lc) ^ sw) * 8]);
        racc[vt] = __builtin_amdgcn_mfma_f32_16x16x32_bf16(pf[ks], vf, racc[vt], 0, 0, 0);
      }
    }

    __syncthreads();   // drains staging (vmcnt0) + all waves done with buf
    buf ^= 1;
  }

  // ---- row-sum reduce across the 16 key-lanes ----
  #pragma unroll
  for (int r = 0; r < 4; ++r) {
    float v = lsum[r];
    #pragma unroll
    for (int msk = 8; msk; msk >>= 1) v += __shfl_xor(v, msk, 64);
    lsum[r] = v;
  }
  float inv[4];
  #pragma unroll
  for (int r = 0; r < 4; ++r) inv[r] = 1.f / lsum[r];

  // ---- write rb[bh][v][l] (bf16), 8B packed per vt ----
  unsigned short* Rb = rb + (size_t)bh * DVD * LL;
  #pragma unroll
  for (int vt = 0; vt < 8; ++vt) {
    ushort4v pk;
    #pragma unroll
    for (int r = 0; r < 4; ++r) pk[r] = f2bf(racc[vt][r] * inv[r]);
    *reinterpret_cast<ushort4v*>(Rb + (size_t)(vt * 16 + lr) * LL + l0w + lc * 4) = pk;
  }
}

// ---------------------------------------------------------------------------
// Kernel 3: merge 1x1 conv + bias + residual (fp32). (unchanged from R9)
// ---------------------------------------------------------------------------
__global__ __launch_bounds__(256) void mhsa_merge_kernel(
    const unsigned short* __restrict__ rb,
    const float* __restrict__ Wm,
    const float* __restrict__ bm,
    const float* __restrict__ x,
    float* __restrict__ out)
{
  const int l0 = blockIdx.x * 64;
  const int o0 = blockIdx.y * 64;
  const int b  = blockIdx.z;

  __shared__ float WmT[32][68];
  __shared__ float Rs[32][68];

  const int tid = threadIdx.x;
  const int to  = tid >> 4;
  const int tl  = tid & 15;

  float acc[4][4];
  #pragma unroll
  for (int r = 0; r < 4; ++r)
    #pragma unroll
    for (int j = 0; j < 4; ++j) acc[r][j] = 0.f;

  for (int c0 = 0; c0 < CC; c0 += 32) {
    __syncthreads();
    #pragma unroll
    for (int i = 0; i < 8; ++i) {
      int flat = tid + 256 * i;
      int o = flat >> 5, c = flat & 31;
      WmT[c][o] = Wm[(size_t)(o0 + o) * CC + c0 + c];
    }
    #pragma unroll
    for (int i = 0; i < 8; ++i) {
      int flat = tid + 256 * i;
      int c = flat >> 6, l = flat & 63;
      Rs[c][l] = bf2f(rb[((size_t)b * CC + c0 + c) * LL + l0 + l]);
    }
    __syncthreads();
    #pragma unroll 4
    for (int cc = 0; cc < 32; ++cc) {
      f32x4 wv = *(const f32x4*)&WmT[cc][to * 4];
      f32x4 rv = *(const f32x4*)&Rs[cc][tl * 4];
      #pragma unroll
      for (int r = 0; r < 4; ++r)
        #pragma unroll
        for (int j = 0; j < 4; ++j) acc[r][j] += wv[r] * rv[j];
    }
  }

  #pragma unroll
  for (int r = 0; r < 4; ++r) {
    int o = o0 + to * 4 + r;
    float bias = bm[o];
    size_t off = ((size_t)b * CC + o) * LL + l0 + tl * 4;
    f32x4 xv = *reinterpret_cast<const f32x4*>(x + off);
    f32x4 ov;
    #pragma unroll
    for (int j = 0; j < 4; ++j) ov[j] = acc[r][j] + bias + xv[j];
    *reinterpret_cast<f32x4*>(out + off) = ov;
  }
}

// ---------------------------------------------------------------------------
extern "C" void kernel_launch(void* const* d_in, const int* in_sizes, int n_in,
                              void* d_out, int out_size, void* d_ws, size_t ws_size,
                              hipStream_t stream) {
  const float* x     = (const float*)d_in[0];
  const float* Wq    = (const float*)d_in[1];
  const float* bq    = (const float*)d_in[2];
  const float* Wk    = (const float*)d_in[3];
  const float* bk    = (const float*)d_in[4];
  const float* Wv    = (const float*)d_in[5];
  const float* bv    = (const float*)d_in[6];
  const float* scale = (const float*)d_in[7];
  const float* Wm    = (const float*)d_in[8];
  const float* bm    = (const float*)d_in[9];
  float* out = (float*)d_out;

  const size_t nqk = (size_t)BB * NHD * LL * DKD;   // elements per q/k/v buffer
  unsigned short* qn = (unsigned short*)d_ws;
  unsigned short* kn = qn + nqk;
  unsigned short* vb = kn + nqk;
  unsigned short* rb = vb + nqk;                    // [B][NH*DV][L]

  mhsa_proj_kernel<<<dim3(LL / 32, BB * NHD, 3), dim3(256), 0, stream>>>(
      x, Wq, bq, Wk, bk, Wv, bv, scale, qn, kn, vb);
  mhsa_attn_kernel<<<dim3(LL / QBLK, BB * NHD), dim3(256), 0, stream>>>(
      qn, kn, vb, scale, rb);
  mhsa_merge_kernel<<<dim3(LL / 64, CC / 64, BB), dim3(256), 0, stream>>>(
      rb, Wm, bm, x, out);
}

// Round 12
// 142.995 us; speedup vs baseline: 2.7829x; 1.5103x over previous
//
#include <hip/hip_runtime.h>

// R12: attn split-K=2 across blocks (512 blocks -> 2 blocks/CU, 2 waves/SIMD).
// R10 diagnosis: 4575 cy/tile vs ~900 cy work, 1 wave/SIMD -> every latency
// exposed. Static-max softmax makes cross-block combine additive; merge kernel
// folds it into its staging step. rb buffer replaced by bf16 partials + f32
// partial row-sums (ws ~20.1 MB).

// Problem constants
#define BB  2
#define CC  256
#define LL  4096   // 64*64 spatial tokens
#define NHD 2
#define DKD 128
#define DVD 128

#define QBLK   64
#define KVBLK  64
#define SPLITK 2
#define TPS    (LL / SPLITK / KVBLK)   // 32 tiles per split

typedef short  short8  __attribute__((ext_vector_type(8)));
typedef float  f32x4   __attribute__((ext_vector_type(4)));
typedef unsigned short ushort4v __attribute__((ext_vector_type(4)));

__device__ __forceinline__ unsigned short f2bf(float f) {
  union { float f; unsigned u; } v; v.f = f;
  unsigned r = v.u + 0x7fffu + ((v.u >> 16) & 1u);   // RNE
  return (unsigned short)(r >> 16);
}
__device__ __forceinline__ float bf2f(unsigned short u) {
  union { unsigned u; float f; } v; v.u = ((unsigned)u) << 16;
  return v.f;
}
__device__ __forceinline__ void glds16(const unsigned short* g, unsigned short* l) {
  __builtin_amdgcn_global_load_lds(
      (const __attribute__((address_space(1))) void*)g,
      (__attribute__((address_space(3))) void*)l, 16, 0, 0);
}

// ---------------------------------------------------------------------------
// Kernel 1: QKV 1x1-conv projections (fp32), fused l2-norm for Q/K, bf16 out.
// grid (L/32, B*NH, 3)  block 256.  (unchanged — passing since R1)
// ---------------------------------------------------------------------------
__global__ __launch_bounds__(256) void mhsa_proj_kernel(
    const float* __restrict__ x,
    const float* __restrict__ Wq, const float* __restrict__ bq,
    const float* __restrict__ Wk, const float* __restrict__ bk,
    const float* __restrict__ Wv, const float* __restrict__ bv,
    const float* __restrict__ scale,
    unsigned short* __restrict__ qn,
    unsigned short* __restrict__ kn,
    unsigned short* __restrict__ vb)
{
  const int lt = blockIdx.x * 32;
  const int bh = blockIdx.y;           // b*NH + h
  const int h  = bh % NHD;
  const int b  = bh / NHD;
  const int p  = blockIdx.z;           // 0=Q 1=K 2=V

  const float* W    = (p == 0 ? Wq : (p == 1 ? Wk : Wv)) + (size_t)h * DKD * CC;
  const float* bias = (p == 0 ? bq : (p == 1 ? bk : bv)) + h * DKD;

  __shared__ float WsT[32][132];
  __shared__ float Xs[32][33];
  __shared__ float red[16][32];
  __shared__ float ninv[32];

  const int tid = threadIdx.x;
  const int tk  = tid >> 4;
  const int tl  = tid & 15;

  float acc[8][2];
  #pragma unroll
  for (int r = 0; r < 8; ++r) { acc[r][0] = 0.f; acc[r][1] = 0.f; }

  const float* xb = x + (size_t)b * CC * LL;

  for (int c0 = 0; c0 < CC; c0 += 32) {
    __syncthreads();
    #pragma unroll
    for (int i = 0; i < 16; ++i) {
      int flat = tid + 256 * i;
      int k = flat >> 5, c = flat & 31;
      WsT[c][k] = W[(size_t)k * CC + c0 + c];
    }
    #pragma unroll
    for (int i = 0; i < 4; ++i) {
      int flat = tid + 256 * i;
      int c = flat >> 5, l = flat & 31;
      Xs[c][l] = xb[(size_t)(c0 + c) * LL + lt + l];
    }
    __syncthreads();
    #pragma unroll 8
    for (int cc = 0; cc < 32; ++cc) {
      float x0 = Xs[cc][tl * 2 + 0];
      float x1 = Xs[cc][tl * 2 + 1];
      f32x4 w0 = *(const f32x4*)&WsT[cc][tk * 8 + 0];
      f32x4 w1 = *(const f32x4*)&WsT[cc][tk * 8 + 4];
      #pragma unroll
      for (int r = 0; r < 4; ++r) {
        acc[r][0]     += w0[r] * x0;  acc[r][1]     += w0[r] * x1;
        acc[r + 4][0] += w1[r] * x0;  acc[r + 4][1] += w1[r] * x1;
      }
    }
  }

  #pragma unroll
  for (int r = 0; r < 8; ++r) {
    float bs = bias[tk * 8 + r];
    acc[r][0] += bs;  acc[r][1] += bs;
  }

  if (p < 2) {
    float s0 = 0.f, s1 = 0.f;
    #pragma unroll
    for (int r = 0; r < 8; ++r) { s0 += acc[r][0] * acc[r][0]; s1 += acc[r][1] * acc[r][1]; }
    __syncthreads();
    red[tk][tl * 2 + 0] = s0;
    red[tk][tl * 2 + 1] = s1;
    __syncthreads();
    if (tid < 32) {
      float s = 0.f;
      #pragma unroll
      for (int i = 0; i < 16; ++i) s += red[i][tid];
      ninv[tid] = sqrtf(scale[h]) / fmaxf(sqrtf(s), 1e-6f);
    }
    __syncthreads();
    unsigned short* out = (p == 0 ? qn : kn) + ((size_t)bh * LL + lt) * DKD;
    float n0 = ninv[tl * 2 + 0], n1 = ninv[tl * 2 + 1];
    #pragma unroll
    for (int j = 0; j < 2; ++j) {
      float nv = j ? n1 : n0;
      short8 pk;
      #pragma unroll
      for (int r = 0; r < 8; ++r) pk[r] = (short)f2bf(acc[r][j] * nv);
      *reinterpret_cast<short8*>(out + (size_t)(tl * 2 + j) * DKD + tk * 8) = pk;
    }
  } else {
    unsigned short* out = vb + (size_t)bh * DVD * LL;
    #pragma unroll
    for (int r = 0; r < 8; ++r) {
      unsigned pk = (unsigned)f2bf(acc[r][0]) | ((unsigned)f2bf(acc[r][1]) << 16);
      *reinterpret_cast<unsigned*>(out + (size_t)(tk * 8 + r) * LL + lt + tl * 2) = pk;
    }
  }
}

// ---------------------------------------------------------------------------
// Kernel 2: flash attention, 64 q-rows/block, split-K=2, LDS-staged K/V.
// grid 512 blocks (2/CU): wgid -> xcd=wgid&7 (bh=xcd>>1), slot=wgid>>3:
// qt = ((xcd&1)<<5)|(slot&31), s = slot>>5. Each block: 64 q-rows x 2048 keys
// (32 tiles), K/V staged via global_load_lds w16, double-buffered, chunk-XOR
// swizzle on BOTH global source and LDS read (G21 involution).
// STATIC-MAX softmax (M = scale[h] exact). Partials: pr bf16 [s][bh][v][l],
// ls f32 [s][bh][l]; combine is additive, folded into merge kernel.
// ---------------------------------------------------------------------------
__global__ __launch_bounds__(256) void mhsa_attn_kernel(
    const unsigned short* __restrict__ qn,
    const unsigned short* __restrict__ kn,
    const unsigned short* __restrict__ vb,
    const float* __restrict__ scale,
    unsigned short* __restrict__ pr,
    float* __restrict__ ls)
{
  const int wgid = (blockIdx.z * gridDim.y + blockIdx.y) * gridDim.x + blockIdx.x;
  const int xcd  = wgid & 7;
  const int slot = wgid >> 3;                 // 0..63
  const int bh   = xcd >> 1;                  // 0..3
  const int qt   = ((xcd & 1) << 5) | (slot & 31);   // 0..63
  const int s    = slot >> 5;                 // split 0/1
  const int l0   = qt * QBLK;
  const int kbase = s * (LL / SPLITK);        // 0 or 2048

  const int wave = threadIdx.x >> 6;
  const int lane = threadIdx.x & 63;
  const int lr   = lane & 15;
  const int lc   = lane >> 4;

  const unsigned short* Q = qn + (size_t)bh * LL * DKD;
  const unsigned short* K = kn + (size_t)bh * LL * DKD;
  const unsigned short* V = vb + (size_t)bh * DVD * LL;
  const float M = scale[bh & 1];              // exact row max of S

  __shared__ unsigned short Ks[2][KVBLK * DKD];   // 2 x 16KB
  __shared__ unsigned short Vs[2][DVD * KVBLK];   // 2 x 16KB
  __shared__ unsigned short plds[4][16 * 72];     // per-wave P tile (+pad)
  unsigned short* myp = plds[wave];

  // ---- Q fragments (once) ----
  const int l0w = l0 + wave * 16;
  short8 qf[4];
  #pragma unroll
  for (int ks = 0; ks < 4; ++ks)
    qf[ks] = *reinterpret_cast<const short8*>(Q + (size_t)(l0w + lr) * DKD + ks * 32 + lc * 8);

  // ---- per-lane staging offsets (ushort units), instr i = wave*4+j ----
  int offK[4], offV[4], ldsOff[4];
  #pragma unroll
  for (int j = 0; j < 4; ++j) {
    int ii = wave * 4 + j;                    // 0..15
    int rK = ii * 4 + (lane >> 4);            // K row 0..63
    int cK = (lane & 15) ^ (rK & 7);          // pre-swizzled 16B chunk
    offK[j] = rK * DKD + cK * 8;
    int vV = ii * 8 + (lane >> 3);            // V row 0..127
    int cV = (lane & 7) ^ (lane >> 3);        // (vV&7) == lane>>3
    offV[j] = vV * LL + cV * 8;
    ldsOff[j] = ii * 512;                     // 1KB per instr
  }

  f32x4 racc[8];
  #pragma unroll
  for (int vt = 0; vt < 8; ++vt) racc[vt] = (f32x4){0.f, 0.f, 0.f, 0.f};
  float lsum[4] = {0.f, 0.f, 0.f, 0.f};

  // ---- prologue: stage tile 0 of this split into buf 0 ----
  #pragma unroll
  for (int j = 0; j < 4; ++j) {
    glds16(K + (size_t)kbase * DKD + offK[j], &Ks[0][ldsOff[j]]);
    glds16(V + kbase + offV[j],               &Vs[0][ldsOff[j]]);
  }
  __syncthreads();

  const int sw = lr & 7;
  int buf = 0;
  for (int t = 0; t < TPS; ++t) {
    if (t + 1 < TPS) {
      int m1 = kbase + (t + 1) * KVBLK;
      #pragma unroll
      for (int j = 0; j < 4; ++j) {
        glds16(K + (size_t)m1 * DKD + offK[j], &Ks[buf ^ 1][ldsOff[j]]);
        glds16(V + m1 + offV[j],               &Vs[buf ^ 1][ldsOff[j]]);
      }
    }

    // ---- S tile: 16 q-rows x 64 keys (K from LDS, swizzled read) ----
    f32x4 sx[4];
    #pragma unroll
    for (int ct = 0; ct < 4; ++ct) {
      f32x4 acc = (f32x4){0.f, 0.f, 0.f, 0.f};
      #pragma unroll
      for (int ks = 0; ks < 4; ++ks) {
        short8 kf = *reinterpret_cast<const short8*>(
            &Ks[buf][(ct * 16 + lr) * DKD + ((ks * 4 + lc) ^ sw) * 8]);
        acc = __builtin_amdgcn_mfma_f32_16x16x32_bf16(qf[ks], kf, acc, 0, 0, 0);
      }
      sx[ct] = acc;
    }

    // ---- P = exp(S - M), in-register row-sum ----
    #pragma unroll
    for (int ct = 0; ct < 4; ++ct) {
      #pragma unroll
      for (int r = 0; r < 4; ++r) {
        float pv = __expf(sx[ct][r] - M);
        sx[ct][r] = pv;
        lsum[r] += pv;
      }
    }

    // ---- P -> per-wave LDS (bf16), D-frag -> A-frag re-layout ----
    #pragma unroll
    for (int ct = 0; ct < 4; ++ct)
      #pragma unroll
      for (int r = 0; r < 4; ++r)
        myp[(lc * 4 + r) * 72 + ct * 16 + lr] = f2bf(sx[ct][r]);

    short8 pf[2];
    #pragma unroll
    for (int ks = 0; ks < 2; ++ks)
      pf[ks] = *reinterpret_cast<const short8*>(&myp[lr * 72 + ks * 32 + lc * 8]);

    // ---- PV: racc[vt] += P[16x64] . V^T[64x16] (V from LDS, swizzled) ----
    #pragma unroll
    for (int vt = 0; vt < 8; ++vt) {
      #pragma unroll
      for (int ks = 0; ks < 2; ++ks) {
        short8 vf = *reinterpret_cast<const short8*>(
            &Vs[buf][(vt * 16 + lr) * KVBLK + ((ks * 4 + lc) ^ sw) * 8]);
        racc[vt] = __builtin_amdgcn_mfma_f32_16x16x32_bf16(pf[ks], vf, racc[vt], 0, 0, 0);
      }
    }

    __syncthreads();   // drains staging + all waves done with buf
    buf ^= 1;
  }

  // ---- row-sum reduce across the 16 key-lanes; write partial lsum ----
  #pragma unroll
  for (int r = 0; r < 4; ++r) {
    float v = lsum[r];
    #pragma unroll
    for (int msk = 8; msk; msk >>= 1) v += __shfl_xor(v, msk, 64);
    lsum[r] = v;
  }
  if (lr == 0) {
    #pragma unroll
    for (int r = 0; r < 4; ++r)
      ls[((size_t)s * 4 + bh) * LL + l0w + lc * 4 + r] = lsum[r];
  }

  // ---- write bf16 partial PV-sums: pr[s][bh][v][l] ----
  unsigned short* Pb = pr + ((size_t)s * 4 + bh) * DVD * LL;
  #pragma unroll
  for (int vt = 0; vt < 8; ++vt) {
    ushort4v pk;
    #pragma unroll
    for (int r = 0; r < 4; ++r) pk[r] = f2bf(racc[vt][r]);
    *reinterpret_cast<ushort4v*>(Pb + (size_t)(vt * 16 + lr) * LL + l0w + lc * 4) = pk;
  }
}

// ---------------------------------------------------------------------------
// Kernel 3: merge 1x1 conv + bias + residual (fp32), with folded split-K
// combine: R[c][l] = (pr0 + pr1) / (ls0 + ls1).
// grid (L/64, C/64, B)  block 256.
// ---------------------------------------------------------------------------
__global__ __launch_bounds__(256) void mhsa_merge_kernel(
    const unsigned short* __restrict__ pr,
    const float* __restrict__ ls,
    const float* __restrict__ Wm,
    const float* __restrict__ bm,
    const float* __restrict__ x,
    float* __restrict__ out)
{
  const int l0 = blockIdx.x * 64;
  const int o0 = blockIdx.y * 64;
  const int b  = blockIdx.z;

  __shared__ float WmT[32][68];
  __shared__ float Rs[32][68];
  __shared__ float invL[2][64];

  const int tid = threadIdx.x;
  const int to  = tid >> 4;
  const int tl  = tid & 15;

  if (tid < 128) {
    int h = tid >> 6, l = tid & 63;
    size_t bhl = (size_t)(b * NHD + h) * LL + l0 + l;
    float s0 = ls[bhl];
    float s1 = ls[(size_t)4 * LL + bhl];
    invL[h][l] = 1.f / (s0 + s1);
  }

  float acc[4][4];
  #pragma unroll
  for (int r = 0; r < 4; ++r)
    #pragma unroll
    for (int j = 0; j < 4; ++j) acc[r][j] = 0.f;

  const size_t sstride = (size_t)4 * DVD * LL;   // split plane stride in pr

  for (int c0 = 0; c0 < CC; c0 += 32) {
    __syncthreads();
    #pragma unroll
    for (int i = 0; i < 8; ++i) {
      int flat = tid + 256 * i;
      int o = flat >> 5, c = flat & 31;
      WmT[c][o] = Wm[(size_t)(o0 + o) * CC + c0 + c];
    }
    #pragma unroll
    for (int i = 0; i < 8; ++i) {
      int flat = tid + 256 * i;
      int c = flat >> 6, l = flat & 63;
      int ch = c0 + c;
      int h = ch >> 7, v = ch & 127;
      size_t idx = ((size_t)(b * NHD + h) * DVD + v) * LL + l0 + l;
      Rs[c][l] = (bf2f(pr[idx]) + bf2f(pr[sstride + idx])) * invL[h][l];
    }
    __syncthreads();
    #pragma unroll 4
    for (int cc = 0; cc < 32; ++cc) {
      f32x4 wv = *(const f32x4*)&WmT[cc][to * 4];
      f32x4 rv = *(const f32x4*)&Rs[cc][tl * 4];
      #pragma unroll
      for (int r = 0; r < 4; ++r)
        #pragma unroll
        for (int j = 0; j < 4; ++j) acc[r][j] += wv[r] * rv[j];
    }
  }

  #pragma unroll
  for (int r = 0; r < 4; ++r) {
    int o = o0 + to * 4 + r;
    float bias = bm[o];
    size_t off = ((size_t)b * CC + o) * LL + l0 + tl * 4;
    f32x4 xv = *reinterpret_cast<const f32x4*>(x + off);
    f32x4 ov;
    #pragma unroll
    for (int j = 0; j < 4; ++j) ov[j] = acc[r][j] + bias + xv[j];
    *reinterpret_cast<f32x4*>(out + off) = ov;
  }
}

// ---------------------------------------------------------------------------
extern "C" void kernel_launch(void* const* d_in, const int* in_sizes, int n_in,
                              void* d_out, int out_size, void* d_ws, size_t ws_size,
                              hipStream_t stream) {
  const float* x     = (const float*)d_in[0];
  const float* Wq    = (const float*)d_in[1];
  const float* bq    = (const float*)d_in[2];
  const float* Wk    = (const float*)d_in[3];
  const float* bk    = (const float*)d_in[4];
  const float* Wv    = (const float*)d_in[5];
  const float* bv    = (const float*)d_in[6];
  const float* scale = (const float*)d_in[7];
  const float* Wm    = (const float*)d_in[8];
  const float* bm    = (const float*)d_in[9];
  float* out = (float*)d_out;

  const size_t nqk = (size_t)BB * NHD * LL * DKD;   // 2M elements per buffer
  const size_t npr = (size_t)SPLITK * BB * NHD * DVD * LL;  // 4M elements
  unsigned short* qn = (unsigned short*)d_ws;
  unsigned short* kn = qn + nqk;
  unsigned short* vb = kn + nqk;
  unsigned short* pr = vb + nqk;                    // bf16 partials [s][bh][v][l]
  float* lsw = (float*)(pr + npr);                  // f32 partial sums [s][bh][l]

  mhsa_proj_kernel<<<dim3(LL / 32, BB * NHD, 3), dim3(256), 0, stream>>>(
      x, Wq, bq, Wk, bk, Wv, bv, scale, qn, kn, vb);
  mhsa_attn_kernel<<<dim3(LL / QBLK, BB * NHD, SPLITK), dim3(256), 0, stream>>>(
      qn, kn, vb, scale, pr, lsw);
  mhsa_merge_kernel<<<dim3(LL / 64, CC / 64, BB), dim3(256), 0, stream>>>(
      pr, lsw, Wm, bm, x, out);
}

// Round 24
// 104.484 us; speedup vs baseline: 3.8086x; 1.3686x over previous
//
#include <hip/hip_runtime.h>

// R24 resubmission of R13 (round tag only). Eleventh consecutive pod infra
// failure (R13-R23, /tmp exhausted across all push stages). MFMA-proj kernel
// untested and unimplicated (R15 discriminator: known-good R12 failed
// identically). Resubmitting until the pod heals or is rotated.
// R13: proj MFMA-ized. Pre-kernel converts x -> Xt bf16 [b][l][c] (transpose)
// and W -> wbf bf16; proj GEMM uses mfma_16x16x32_bf16 with global_load_lds
// staging + chunk-XOR swizzle (verified pattern from attn). Xt/wbf alias the
// pr region (dead until attn). attn/merge unchanged from R12.

// Problem constants
#define BB  2
#define CC  256
#define LL  4096   // 64*64 spatial tokens
#define NHD 2
#define DKD 128
#define DVD 128

#define QBLK   64
#define KVBLK  64
#define SPLITK 2
#define TPS    (LL / SPLITK / KVBLK)   // 32 tiles per split

typedef short  short8  __attribute__((ext_vector_type(8)));
typedef float  f32x4   __attribute__((ext_vector_type(4)));
typedef unsigned short ushort4v __attribute__((ext_vector_type(4)));

__device__ __forceinline__ unsigned short f2bf(float f) {
  union { float f; unsigned u; } v; v.f = f;
  unsigned r = v.u + 0x7fffu + ((v.u >> 16) & 1u);   // RNE
  return (unsigned short)(r >> 16);
}
__device__ __forceinline__ float bf2f(unsigned short u) {
  union { unsigned u; float f; } v; v.u = ((unsigned)u) << 16;
  return v.f;
}
__device__ __forceinline__ void glds16(const unsigned short* g, unsigned short* l) {
  __builtin_amdgcn_global_load_lds(
      (const __attribute__((address_space(1))) void*)g,
      (__attribute__((address_space(3))) void*)l, 16, 0, 0);
}

// ---------------------------------------------------------------------------
// Kernel 0: precompute — z<2: transpose+convert x[b] fp32 [c][l] -> Xt bf16
// [l][c] (32x32 LDS tiles); z==2,y==0: convert Wq/Wk/Wv -> wbf [p][h][k][c].
// grid (128, 8, 3)  block 256.
// ---------------------------------------------------------------------------
__global__ __launch_bounds__(256) void mhsa_pre_kernel(
    const float* __restrict__ x,
    const float* __restrict__ Wq, const float* __restrict__ Wk,
    const float* __restrict__ Wv,
    unsigned short* __restrict__ Xt, unsigned short* __restrict__ wbf)
{
  const int z = blockIdx.z;
  if (z == 2) {
    if (blockIdx.y) return;
    // 3*2*128*256 = 196608 elements; 128 blocks x 1536
    int base = blockIdx.x * 1536 + threadIdx.x;
    #pragma unroll
    for (int i = 0; i < 6; ++i) {
      int idx = base + i * 256;
      int p = idx >> 16;                  // 65536 per projection
      int rem = idx & 65535;
      const float* W = p == 0 ? Wq : (p == 1 ? Wk : Wv);
      wbf[idx] = f2bf(W[rem]);
    }
    return;
  }
  const int b  = z;
  const int l0 = blockIdx.x * 32, c0 = blockIdx.y * 32;
  __shared__ float Ts[32][33];
  const int tid = threadIdx.x;
  const int tl  = tid & 31, tc = tid >> 5;   // tc 0..7
  const float* xb = x + (size_t)b * CC * LL;
  #pragma unroll
  for (int pp = 0; pp < 4; ++pp) {
    int c = tc + pp * 8;
    Ts[c][tl] = xb[(size_t)(c0 + c) * LL + l0 + tl];
  }
  __syncthreads();
  unsigned short* Xb = Xt + (size_t)b * LL * CC;
  #pragma unroll
  for (int pp = 0; pp < 4; ++pp) {
    int l = tc + pp * 8;
    Xb[(size_t)(l0 + l) * CC + c0 + tl] = f2bf(Ts[tl][l]);
  }
}

// ---------------------------------------------------------------------------
// Kernel 1: QKV projections via MFMA (bf16 in, fp32 acc), fused l2-norm.
// grid (64 l-tiles, 4 bh, 3 p)  block 256 (4 waves), 768 blocks = 3/CU.
// Block: C[128 k][64 l] = W[128][256] x X^T; K-loop 4 steps of 64c,
// double-buffered LDS, glds16 staging with chunk-XOR swizzle (G21).
// ---------------------------------------------------------------------------
__global__ __launch_bounds__(256) void mhsa_projm_kernel(
    const unsigned short* __restrict__ Xt,
    const unsigned short* __restrict__ wbf,
    const float* __restrict__ bq, const float* __restrict__ bk,
    const float* __restrict__ bv, const float* __restrict__ scale,
    unsigned short* __restrict__ qn, unsigned short* __restrict__ kn,
    unsigned short* __restrict__ vb)
{
  const int lt0 = blockIdx.x * 64;
  const int bh  = blockIdx.y;            // b*2 + h
  const int p   = blockIdx.z;
  const int h   = bh & 1, b = bh >> 1;

  const unsigned short* W = wbf + ((size_t)p * 2 + h) * (128 * 256);
  const unsigned short* X = Xt + (size_t)b * LL * CC;
  const float* bias = (p == 0 ? bq : (p == 1 ? bk : bv)) + h * 128;

  __shared__ unsigned short Ws[2][128 * 64];   // 2 x 16KB
  __shared__ unsigned short Xs[2][64 * 64];    // 2 x 8KB
  __shared__ float red[4][64];

  const int wave = threadIdx.x >> 6;
  const int lane = threadIdx.x & 63;
  const int lr = lane & 15, lc = lane >> 4;

  // staging offsets (u16 units); rows have 8 chunks of 16B; 8 rows/instr
  int offW[4], ldsW[4], offX[2], ldsX[2];
  #pragma unroll
  for (int j = 0; j < 4; ++j) {
    int ii = wave * 4 + j;                 // 0..15 -> W rows ii*8..ii*8+7
    int r  = ii * 8 + (lane >> 3);
    int c  = (lane & 7) ^ (lane >> 3);     // pre-swizzle: r&7 == lane>>3
    offW[j] = r * 256 + c * 8;
    ldsW[j] = ii * 512;
  }
  #pragma unroll
  for (int j = 0; j < 2; ++j) {
    int ii = wave * 2 + j;                 // 0..7 -> X rows ii*8..ii*8+7
    int r  = ii * 8 + (lane >> 3);
    int c  = (lane & 7) ^ (lane >> 3);
    offX[j] = (lt0 + r) * 256 + c * 8;
    ldsX[j] = ii * 512;
  }

  f32x4 acc[2][4];
  #pragma unroll
  for (int kt2 = 0; kt2 < 2; ++kt2)
    #pragma unroll
    for (int lt = 0; lt < 4; ++lt) acc[kt2][lt] = (f32x4){0.f, 0.f, 0.f, 0.f};

  #pragma unroll
  for (int j = 0; j < 4; ++j) glds16(W + offW[j], &Ws[0][ldsW[j]]);
  #pragma unroll
  for (int j = 0; j < 2; ++j) glds16(X + offX[j], &Xs[0][ldsX[j]]);
  __syncthreads();

  const int sw = lr & 7;
  int buf = 0;
  for (int step = 0; step < 4; ++step) {
    if (step < 3) {
      int c0 = (step + 1) * 64;
      #pragma unroll
      for (int j = 0; j < 4; ++j) glds16(W + c0 + offW[j], &Ws[buf ^ 1][ldsW[j]]);
      #pragma unroll
      for (int j = 0; j < 2; ++j) glds16(X + c0 + offX[j], &Xs[buf ^ 1][ldsX[j]]);
    }
    #pragma unroll
    for (int ks = 0; ks < 2; ++ks) {
      short8 af[2], bf_[4];
      #pragma unroll
      for (int kt2 = 0; kt2 < 2; ++kt2)
        af[kt2] = *reinterpret_cast<const short8*>(
            &Ws[buf][(wave * 32 + kt2 * 16 + lr) * 64 + ((ks * 4 + lc) ^ sw) * 8]);
      #pragma unroll
      for (int lt = 0; lt < 4; ++lt)
        bf_[lt] = *reinterpret_cast<const short8*>(
            &Xs[buf][(lt * 16 + lr) * 64 + ((ks * 4 + lc) ^ sw) * 8]);
      #pragma unroll
      for (int kt2 = 0; kt2 < 2; ++kt2)
        #pragma unroll
        for (int lt = 0; lt < 4; ++lt)
          acc[kt2][lt] = __builtin_amdgcn_mfma_f32_16x16x32_bf16(
              af[kt2], bf_[lt], acc[kt2][lt], 0, 0, 0);
    }
    __syncthreads();
    buf ^= 1;
  }

  // bias: k = wave*32 + kt2*16 + lc*4 + r (D row = lc*4+reg)
  #pragma unroll
  for (int kt2 = 0; kt2 < 2; ++kt2)
    #pragma unroll
    for (int r = 0; r < 4; ++r) {
      float bsv = bias[wave * 32 + kt2 * 16 + lc * 4 + r];
      #pragma unroll
      for (int lt = 0; lt < 4; ++lt) acc[kt2][lt][r] += bsv;
    }

  if (p < 2) {
    // column l2-norm over all 128 k
    float s[4];
    #pragma unroll
    for (int lt = 0; lt < 4; ++lt) {
      float v = 0.f;
      #pragma unroll
      for (int kt2 = 0; kt2 < 2; ++kt2)
        #pragma unroll
        for (int r = 0; r < 4; ++r) v += acc[kt2][lt][r] * acc[kt2][lt][r];
      v += __shfl_xor(v, 16, 64);
      v += __shfl_xor(v, 32, 64);
      s[lt] = v;                            // sum over this wave's 32 k
    }
    if (lc == 0) {
      #pragma unroll
      for (int lt = 0; lt < 4; ++lt) red[wave][lt * 16 + lr] = s[lt];
    }
    __syncthreads();
    float sq = sqrtf(scale[h]);
    unsigned short* out = (p == 0 ? qn : kn) + (size_t)bh * LL * DKD;
    #pragma unroll
    for (int lt = 0; lt < 4; ++lt) {
      int l = lt * 16 + lr;
      float sum = red[0][l] + red[1][l] + red[2][l] + red[3][l];
      float nv = sq / fmaxf(sqrtf(sum), 1e-6f);
      #pragma unroll
      for (int kt2 = 0; kt2 < 2; ++kt2) {
        ushort4v pk;
        #pragma unroll
        for (int r = 0; r < 4; ++r) pk[r] = f2bf(acc[kt2][lt][r] * nv);
        *reinterpret_cast<ushort4v*>(
            out + (size_t)(lt0 + l) * DKD + wave * 32 + kt2 * 16 + lc * 4) = pk;
      }
    }
  } else {
    unsigned short* outv = vb + (size_t)bh * DVD * LL;
    #pragma unroll
    for (int kt2 = 0; kt2 < 2; ++kt2)
      #pragma unroll
      for (int r = 0; r < 4; ++r)
        #pragma unroll
        for (int lt = 0; lt < 4; ++lt)
          outv[(size_t)(wave * 32 + kt2 * 16 + lc * 4 + r) * LL + lt0 + lt * 16 + lr]
              = f2bf(acc[kt2][lt][r]);
  }
}

// ---------------------------------------------------------------------------
// Kernel 2: flash attention (unchanged from R12 — 75us, prediction matched).
// ---------------------------------------------------------------------------
__global__ __launch_bounds__(256) void mhsa_attn_kernel(
    const unsigned short* __restrict__ qn,
    const unsigned short* __restrict__ kn,
    const unsigned short* __restrict__ vb,
    const float* __restrict__ scale,
    unsigned short* __restrict__ pr,
    float* __restrict__ ls)
{
  const int wgid = (blockIdx.z * gridDim.y + blockIdx.y) * gridDim.x + blockIdx.x;
  const int xcd  = wgid & 7;
  const int slot = wgid >> 3;                 // 0..63
  const int bh   = xcd >> 1;                  // 0..3
  const int qt   = ((xcd & 1) << 5) | (slot & 31);   // 0..63
  const int s    = slot >> 5;                 // split 0/1
  const int l0   = qt * QBLK;
  const int kbase = s * (LL / SPLITK);        // 0 or 2048

  const int wave = threadIdx.x >> 6;
  const int lane = threadIdx.x & 63;
  const int lr   = lane & 15;
  const int lc   = lane >> 4;

  const unsigned short* Q = qn + (size_t)bh * LL * DKD;
  const unsigned short* K = kn + (size_t)bh * LL * DKD;
  const unsigned short* V = vb + (size_t)bh * DVD * LL;
  const float M = scale[bh & 1];              // exact row max of S

  __shared__ unsigned short Ks[2][KVBLK * DKD];   // 2 x 16KB
  __shared__ unsigned short Vs[2][DVD * KVBLK];   // 2 x 16KB
  __shared__ unsigned short plds[4][16 * 72];     // per-wave P tile (+pad)
  unsigned short* myp = plds[wave];

  const int l0w = l0 + wave * 16;
  short8 qf[4];
  #pragma unroll
  for (int ks = 0; ks < 4; ++ks)
    qf[ks] = *reinterpret_cast<const short8*>(Q + (size_t)(l0w + lr) * DKD + ks * 32 + lc * 8);

  int offK[4], offV[4], ldsOff[4];
  #pragma unroll
  for (int j = 0; j < 4; ++j) {
    int ii = wave * 4 + j;                    // 0..15
    int rK = ii * 4 + (lane >> 4);            // K row 0..63
    int cK = (lane & 15) ^ (rK & 7);          // pre-swizzled 16B chunk
    offK[j] = rK * DKD + cK * 8;
    int vV = ii * 8 + (lane >> 3);            // V row 0..127
    int cV = (lane & 7) ^ (lane >> 3);        // (vV&7) == lane>>3
    offV[j] = vV * LL + cV * 8;
    ldsOff[j] = ii * 512;                     // 1KB per instr
  }

  f32x4 racc[8];
  #pragma unroll
  for (int vt = 0; vt < 8; ++vt) racc[vt] = (f32x4){0.f, 0.f, 0.f, 0.f};
  float lsum[4] = {0.f, 0.f, 0.f, 0.f};

  #pragma unroll
  for (int j = 0; j < 4; ++j) {
    glds16(K + (size_t)kbase * DKD + offK[j], &Ks[0][ldsOff[j]]);
    glds16(V + kbase + offV[j],               &Vs[0][ldsOff[j]]);
  }
  __syncthreads();

  const int sw = lr & 7;
  int buf = 0;
  for (int t = 0; t < TPS; ++t) {
    if (t + 1 < TPS) {
      int m1 = kbase + (t + 1) * KVBLK;
      #pragma unroll
      for (int j = 0; j < 4; ++j) {
        glds16(K + (size_t)m1 * DKD + offK[j], &Ks[buf ^ 1][ldsOff[j]]);
        glds16(V + m1 + offV[j],               &Vs[buf ^ 1][ldsOff[j]]);
      }
    }

    f32x4 sx[4];
    #pragma unroll
    for (int ct = 0; ct < 4; ++ct) {
      f32x4 acc = (f32x4){0.f, 0.f, 0.f, 0.f};
      #pragma unroll
      for (int ks = 0; ks < 4; ++ks) {
        short8 kf = *reinterpret_cast<const short8*>(
            &Ks[buf][(ct * 16 + lr) * DKD + ((ks * 4 + lc) ^ sw) * 8]);
        acc = __builtin_amdgcn_mfma_f32_16x16x32_bf16(qf[ks], kf, acc, 0, 0, 0);
      }
      sx[ct] = acc;
    }

    #pragma unroll
    for (int ct = 0; ct < 4; ++ct) {
      #pragma unroll
      for (int r = 0; r < 4; ++r) {
        float pv = __expf(sx[ct][r] - M);
        sx[ct][r] = pv;
        lsum[r] += pv;
      }
    }

    #pragma unroll
    for (int ct = 0; ct < 4; ++ct)
      #pragma unroll
      for (int r = 0; r < 4; ++r)
        myp[(lc * 4 + r) * 72 + ct * 16 + lr] = f2bf(sx[ct][r]);

    short8 pf[2];
    #pragma unroll
    for (int ks = 0; ks < 2; ++ks)
      pf[ks] = *reinterpret_cast<const short8*>(&myp[lr * 72 + ks * 32 + lc * 8]);

    #pragma unroll
    for (int vt = 0; vt < 8; ++vt) {
      #pragma unroll
      for (int ks = 0; ks < 2; ++ks) {
        short8 vf = *reinterpret_cast<const short8*>(
            &Vs[buf][(vt * 16 + lr) * KVBLK + ((ks * 4 + lc) ^ sw) * 8]);
        racc[vt] = __builtin_amdgcn_mfma_f32_16x16x32_bf16(pf[ks], vf, racc[vt], 0, 0, 0);
      }
    }

    __syncthreads();
    buf ^= 1;
  }

  #pragma unroll
  for (int r = 0; r < 4; ++r) {
    float v = lsum[r];
    #pragma unroll
    for (int msk = 8; msk; msk >>= 1) v += __shfl_xor(v, msk, 64);
    lsum[r] = v;
  }
  if (lr == 0) {
    #pragma unroll
    for (int r = 0; r < 4; ++r)
      ls[((size_t)s * 4 + bh) * LL + l0w + lc * 4 + r] = lsum[r];
  }

  unsigned short* Pb = pr + ((size_t)s * 4 + bh) * DVD * LL;
  #pragma unroll
  for (int vt = 0; vt < 8; ++vt) {
    ushort4v pk;
    #pragma unroll
    for (int r = 0; r < 4; ++r) pk[r] = f2bf(racc[vt][r]);
    *reinterpret_cast<ushort4v*>(Pb + (size_t)(vt * 16 + lr) * LL + l0w + lc * 4) = pk;
  }
}

// ---------------------------------------------------------------------------
// Kernel 3: merge 1x1 conv + bias + residual (fp32), folded split-K combine.
// (unchanged from R12)
// ---------------------------------------------------------------------------
__global__ __launch_bounds__(256) void mhsa_merge_kernel(
    const unsigned short* __restrict__ pr,
    const float* __restrict__ ls,
    const float* __restrict__ Wm,
    const float* __restrict__ bm,
    const float* __restrict__ x,
    float* __restrict__ out)
{
  const int l0 = blockIdx.x * 64;
  const int o0 = blockIdx.y * 64;
  const int b  = blockIdx.z;

  __shared__ float WmT[32][68];
  __shared__ float Rs[32][68];
  __shared__ float invL[2][64];

  const int tid = threadIdx.x;
  const int to  = tid >> 4;
  const int tl  = tid & 15;

  if (tid < 128) {
    int h = tid >> 6, l = tid & 63;
    size_t bhl = (size_t)(b * NHD + h) * LL + l0 + l;
    float s0 = ls[bhl];
    float s1 = ls[(size_t)4 * LL + bhl];
    invL[h][l] = 1.f / (s0 + s1);
  }

  float acc[4][4];
  #pragma unroll
  for (int r = 0; r < 4; ++r)
    #pragma unroll
    for (int j = 0; j < 4; ++j) acc[r][j] = 0.f;

  const size_t sstride = (size_t)4 * DVD * LL;

  for (int c0 = 0; c0 < CC; c0 += 32) {
    __syncthreads();
    #pragma unroll
    for (int i = 0; i < 8; ++i) {
      int flat = tid + 256 * i;
      int o = flat >> 5, c = flat & 31;
      WmT[c][o] = Wm[(size_t)(o0 + o) * CC + c0 + c];
    }
    #pragma unroll
    for (int i = 0; i < 8; ++i) {
      int flat = tid + 256 * i;
      int c = flat >> 6, l = flat & 63;
      int ch = c0 + c;
      int hh = ch >> 7, v = ch & 127;
      size_t idx = ((size_t)(b * NHD + hh) * DVD + v) * LL + l0 + l;
      Rs[c][l] = (bf2f(pr[idx]) + bf2f(pr[sstride + idx])) * invL[hh][l];
    }
    __syncthreads();
    #pragma unroll 4
    for (int cc = 0; cc < 32; ++cc) {
      f32x4 wv = *(const f32x4*)&WmT[cc][to * 4];
      f32x4 rv = *(const f32x4*)&Rs[cc][tl * 4];
      #pragma unroll
      for (int r = 0; r < 4; ++r)
        #pragma unroll
        for (int j = 0; j < 4; ++j) acc[r][j] += wv[r] * rv[j];
    }
  }

  #pragma unroll
  for (int r = 0; r < 4; ++r) {
    int o = o0 + to * 4 + r;
    float bias = bm[o];
    size_t off = ((size_t)b * CC + o) * LL + l0 + tl * 4;
    f32x4 xv = *reinterpret_cast<const f32x4*>(x + off);
    f32x4 ov;
    #pragma unroll
    for (int j = 0; j < 4; ++j) ov[j] = acc[r][j] + bias + xv[j];
    *reinterpret_cast<f32x4*>(out + off) = ov;
  }
}

// ---------------------------------------------------------------------------
extern "C" void kernel_launch(void* const* d_in, const int* in_sizes, int n_in,
                              void* d_out, int out_size, void* d_ws, size_t ws_size,
                              hipStream_t stream) {
  const float* x     = (const float*)d_in[0];
  const float* Wq    = (const float*)d_in[1];
  const float* bq    = (const float*)d_in[2];
  const float* Wk    = (const float*)d_in[3];
  const float* bk    = (const float*)d_in[4];
  const float* Wv    = (const float*)d_in[5];
  const float* bv    = (const float*)d_in[6];
  const float* scale = (const float*)d_in[7];
  const float* Wm    = (const float*)d_in[8];
  const float* bm    = (const float*)d_in[9];
  float* out = (float*)d_out;

  const size_t nqk = (size_t)BB * NHD * LL * DKD;            // 4.19M elems
  const size_t npr = (size_t)SPLITK * BB * NHD * DVD * LL;   // 8.39M elems
  unsigned short* qn = (unsigned short*)d_ws;
  unsigned short* kn = qn + nqk;
  unsigned short* vb = kn + nqk;
  unsigned short* pr = vb + nqk;                 // bf16 partials [s][bh][v][l]
  float* lsw = (float*)(pr + npr);               // f32 partial sums [s][bh][l]
  // Xt/wbf alias pr (dead until attn): Xt bf16 [b][l][c], wbf [p][h][k][c]
  unsigned short* Xt  = pr;                      // 2.10M elems
  unsigned short* wbf = pr + (size_t)BB * LL * CC;   // 196K elems (< npr total)

  mhsa_pre_kernel<<<dim3(128, 8, 3), dim3(256), 0, stream>>>(
      x, Wq, Wk, Wv, Xt, wbf);
  mhsa_projm_kernel<<<dim3(LL / 64, BB * NHD, 3), dim3(256), 0, stream>>>(
      Xt, wbf, bq, bk, bv, scale, qn, kn, vb);
  mhsa_attn_kernel<<<dim3(LL / QBLK, BB * NHD, SPLITK), dim3(256), 0, stream>>>(
      qn, kn, vb, scale, pr, lsw);
  mhsa_merge_kernel<<<dim3(LL / 64, CC / 64, BB), dim3(256), 0, stream>>>(
      pr, lsw, Wm, bm, x, out);
}

// Round 32
// 95.485 us; speedup vs baseline: 4.1676x; 1.0942x over previous
//
#include <hip/hip_runtime.h>

// R32 = R25 resubmission (round tag only; clean verified source). Pod still
// disk-full (episode 3, R25-R31). combine/mergem unimplicated (R27
// discriminator ran known-good R24 and failed identically) and untested.
// R25: merge MFMA-ized (projm clone). combine folds split-K reduction +
// transpose into Rt bf16 [b][l][c] (aliases dead qn); mergem = MFMA GEMM
// (Wm bf16 x Rt) + bias + residual fp32 epilogue. pre/projm/attn unchanged
// from R24 (104.5us, passed).

// Problem constants
#define BB  2
#define CC  256
#define LL  4096   // 64*64 spatial tokens
#define NHD 2
#define DKD 128
#define DVD 128

#define QBLK   64
#define KVBLK  64
#define SPLITK 2
#define TPS    (LL / SPLITK / KVBLK)   // 32 tiles per split

typedef short  short8  __attribute__((ext_vector_type(8)));
typedef float  f32x4   __attribute__((ext_vector_type(4)));
typedef unsigned short ushort4v __attribute__((ext_vector_type(4)));

__device__ __forceinline__ unsigned short f2bf(float f) {
  union { float f; unsigned u; } v; v.f = f;
  unsigned r = v.u + 0x7fffu + ((v.u >> 16) & 1u);   // RNE
  return (unsigned short)(r >> 16);
}
__device__ __forceinline__ float bf2f(unsigned short u) {
  union { unsigned u; float f; } v; v.u = ((unsigned)u) << 16;
  return v.f;
}
__device__ __forceinline__ void glds16(const unsigned short* g, unsigned short* l) {
  __builtin_amdgcn_global_load_lds(
      (const __attribute__((address_space(1))) void*)g,
      (__attribute__((address_space(3))) void*)l, 16, 0, 0);
}

// ---------------------------------------------------------------------------
// Kernel 0: precompute — z<2: transpose+convert x[b] fp32 [c][l] -> Xt bf16
// [l][c]; z==2,y==0: convert Wq/Wk/Wv -> wbf and Wm -> wmb (bf16).
// grid (128, 8, 3)  block 256.
// ---------------------------------------------------------------------------
__global__ __launch_bounds__(256) void mhsa_pre_kernel(
    const float* __restrict__ x,
    const float* __restrict__ Wq, const float* __restrict__ Wk,
    const float* __restrict__ Wv, const float* __restrict__ Wm,
    unsigned short* __restrict__ Xt, unsigned short* __restrict__ wbf,
    unsigned short* __restrict__ wmb)
{
  const int z = blockIdx.z;
  if (z == 2) {
    if (blockIdx.y) return;
    // 196608 qkv elements + 65536 Wm elements = 262144; 128 blocks x 2048
    int base = blockIdx.x * 2048 + threadIdx.x;
    #pragma unroll
    for (int i = 0; i < 8; ++i) {
      int idx = base + i * 256;
      if (idx < 196608) {
        int p = idx >> 16;                // 65536 per projection
        int rem = idx & 65535;
        const float* W = p == 0 ? Wq : (p == 1 ? Wk : Wv);
        wbf[idx] = f2bf(W[rem]);
      } else {
        wmb[idx - 196608] = f2bf(Wm[idx - 196608]);
      }
    }
    return;
  }
  const int b  = z;
  const int l0 = blockIdx.x * 32, c0 = blockIdx.y * 32;
  __shared__ float Ts[32][33];
  const int tid = threadIdx.x;
  const int tl  = tid & 31, tc = tid >> 5;   // tc 0..7
  const float* xb = x + (size_t)b * CC * LL;
  #pragma unroll
  for (int pp = 0; pp < 4; ++pp) {
    int c = tc + pp * 8;
    Ts[c][tl] = xb[(size_t)(c0 + c) * LL + l0 + tl];
  }
  __syncthreads();
  unsigned short* Xb = Xt + (size_t)b * LL * CC;
  #pragma unroll
  for (int pp = 0; pp < 4; ++pp) {
    int l = tc + pp * 8;
    Xb[(size_t)(l0 + l) * CC + c0 + tl] = f2bf(Ts[tl][l]);
  }
}

// ---------------------------------------------------------------------------
// Kernel 1: QKV projections via MFMA (bf16 in, fp32 acc), fused l2-norm.
// grid (64 l-tiles, 4 bh, 3 p)  block 256 (4 waves). (unchanged from R24)
// ---------------------------------------------------------------------------
__global__ __launch_bounds__(256) void mhsa_projm_kernel(
    const unsigned short* __restrict__ Xt,
    const unsigned short* __restrict__ wbf,
    const float* __restrict__ bq, const float* __restrict__ bk,
    const float* __restrict__ bv, const float* __restrict__ scale,
    unsigned short* __restrict__ qn, unsigned short* __restrict__ kn,
    unsigned short* __restrict__ vb)
{
  const int lt0 = blockIdx.x * 64;
  const int bh  = blockIdx.y;            // b*2 + h
  const int p   = blockIdx.z;
  const int h   = bh & 1, b = bh >> 1;

  const unsigned short* W = wbf + ((size_t)p * 2 + h) * (128 * 256);
  const unsigned short* X = Xt + (size_t)b * LL * CC;
  const float* bias = (p == 0 ? bq : (p == 1 ? bk : bv)) + h * 128;

  __shared__ unsigned short Ws[2][128 * 64];   // 2 x 16KB
  __shared__ unsigned short Xs[2][64 * 64];    // 2 x 8KB
  __shared__ float red[4][64];

  const int wave = threadIdx.x >> 6;
  const int lane = threadIdx.x & 63;
  const int lr = lane & 15, lc = lane >> 4;

  int offW[4], ldsW[4], offX[2], ldsX[2];
  #pragma unroll
  for (int j = 0; j < 4; ++j) {
    int ii = wave * 4 + j;                 // 0..15 -> W rows ii*8..ii*8+7
    int r  = ii * 8 + (lane >> 3);
    int c  = (lane & 7) ^ (lane >> 3);     // pre-swizzle: r&7 == lane>>3
    offW[j] = r * 256 + c * 8;
    ldsW[j] = ii * 512;
  }
  #pragma unroll
  for (int j = 0; j < 2; ++j) {
    int ii = wave * 2 + j;                 // 0..7 -> X rows ii*8..ii*8+7
    int r  = ii * 8 + (lane >> 3);
    int c  = (lane & 7) ^ (lane >> 3);
    offX[j] = (lt0 + r) * 256 + c * 8;
    ldsX[j] = ii * 512;
  }

  f32x4 acc[2][4];
  #pragma unroll
  for (int kt2 = 0; kt2 < 2; ++kt2)
    #pragma unroll
    for (int lt = 0; lt < 4; ++lt) acc[kt2][lt] = (f32x4){0.f, 0.f, 0.f, 0.f};

  #pragma unroll
  for (int j = 0; j < 4; ++j) glds16(W + offW[j], &Ws[0][ldsW[j]]);
  #pragma unroll
  for (int j = 0; j < 2; ++j) glds16(X + offX[j], &Xs[0][ldsX[j]]);
  __syncthreads();

  const int sw = lr & 7;
  int buf = 0;
  for (int step = 0; step < 4; ++step) {
    if (step < 3) {
      int c0 = (step + 1) * 64;
      #pragma unroll
      for (int j = 0; j < 4; ++j) glds16(W + c0 + offW[j], &Ws[buf ^ 1][ldsW[j]]);
      #pragma unroll
      for (int j = 0; j < 2; ++j) glds16(X + c0 + offX[j], &Xs[buf ^ 1][ldsX[j]]);
    }
    #pragma unroll
    for (int ks = 0; ks < 2; ++ks) {
      short8 af[2], bf_[4];
      #pragma unroll
      for (int kt2 = 0; kt2 < 2; ++kt2)
        af[kt2] = *reinterpret_cast<const short8*>(
            &Ws[buf][(wave * 32 + kt2 * 16 + lr) * 64 + ((ks * 4 + lc) ^ sw) * 8]);
      #pragma unroll
      for (int lt = 0; lt < 4; ++lt)
        bf_[lt] = *reinterpret_cast<const short8*>(
            &Xs[buf][(lt * 16 + lr) * 64 + ((ks * 4 + lc) ^ sw) * 8]);
      #pragma unroll
      for (int kt2 = 0; kt2 < 2; ++kt2)
        #pragma unroll
        for (int lt = 0; lt < 4; ++lt)
          acc[kt2][lt] = __builtin_amdgcn_mfma_f32_16x16x32_bf16(
              af[kt2], bf_[lt], acc[kt2][lt], 0, 0, 0);
    }
    __syncthreads();
    buf ^= 1;
  }

  #pragma unroll
  for (int kt2 = 0; kt2 < 2; ++kt2)
    #pragma unroll
    for (int r = 0; r < 4; ++r) {
      float bsv = bias[wave * 32 + kt2 * 16 + lc * 4 + r];
      #pragma unroll
      for (int lt = 0; lt < 4; ++lt) acc[kt2][lt][r] += bsv;
    }

  if (p < 2) {
    float s[4];
    #pragma unroll
    for (int lt = 0; lt < 4; ++lt) {
      float v = 0.f;
      #pragma unroll
      for (int kt2 = 0; kt2 < 2; ++kt2)
        #pragma unroll
        for (int r = 0; r < 4; ++r) v += acc[kt2][lt][r] * acc[kt2][lt][r];
      v += __shfl_xor(v, 16, 64);
      v += __shfl_xor(v, 32, 64);
      s[lt] = v;
    }
    if (lc == 0) {
      #pragma unroll
      for (int lt = 0; lt < 4; ++lt) red[wave][lt * 16 + lr] = s[lt];
    }
    __syncthreads();
    float sq = sqrtf(scale[h]);
    unsigned short* out = (p == 0 ? qn : kn) + (size_t)bh * LL * DKD;
    #pragma unroll
    for (int lt = 0; lt < 4; ++lt) {
      int l = lt * 16 + lr;
      float sum = red[0][l] + red[1][l] + red[2][l] + red[3][l];
      float nv = sq / fmaxf(sqrtf(sum), 1e-6f);
      #pragma unroll
      for (int kt2 = 0; kt2 < 2; ++kt2) {
        ushort4v pk;
        #pragma unroll
        for (int r = 0; r < 4; ++r) pk[r] = f2bf(acc[kt2][lt][r] * nv);
        *reinterpret_cast<ushort4v*>(
            out + (size_t)(lt0 + l) * DKD + wave * 32 + kt2 * 16 + lc * 4) = pk;
      }
    }
  } else {
    unsigned short* outv = vb + (size_t)bh * DVD * LL;
    #pragma unroll
    for (int kt2 = 0; kt2 < 2; ++kt2)
      #pragma unroll
      for (int r = 0; r < 4; ++r)
        #pragma unroll
        for (int lt = 0; lt < 4; ++lt)
          outv[(size_t)(wave * 32 + kt2 * 16 + lc * 4 + r) * LL + lt0 + lt * 16 + lr]
              = f2bf(acc[kt2][lt][r]);
  }
}

// ---------------------------------------------------------------------------
// Kernel 2: flash attention (unchanged from R12/R24 — 75us measured).
// ---------------------------------------------------------------------------
__global__ __launch_bounds__(256) void mhsa_attn_kernel(
    const unsigned short* __restrict__ qn,
    const unsigned short* __restrict__ kn,
    const unsigned short* __restrict__ vb,
    const float* __restrict__ scale,
    unsigned short* __restrict__ pr,
    float* __restrict__ ls)
{
  const int wgid = (blockIdx.z * gridDim.y + blockIdx.y) * gridDim.x + blockIdx.x;
  const int xcd  = wgid & 7;
  const int slot = wgid >> 3;                 // 0..63
  const int bh   = xcd >> 1;                  // 0..3
  const int qt   = ((xcd & 1) << 5) | (slot & 31);   // 0..63
  const int s    = slot >> 5;                 // split 0/1
  const int l0   = qt * QBLK;
  const int kbase = s * (LL / SPLITK);        // 0 or 2048

  const int wave = threadIdx.x >> 6;
  const int lane = threadIdx.x & 63;
  const int lr   = lane & 15;
  const int lc   = lane >> 4;

  const unsigned short* Q = qn + (size_t)bh * LL * DKD;
  const unsigned short* K = kn + (size_t)bh * LL * DKD;
  const unsigned short* V = vb + (size_t)bh * DVD * LL;
  const float M = scale[bh & 1];              // exact row max of S

  __shared__ unsigned short Ks[2][KVBLK * DKD];   // 2 x 16KB
  __shared__ unsigned short Vs[2][DVD * KVBLK];   // 2 x 16KB
  __shared__ unsigned short plds[4][16 * 72];     // per-wave P tile (+pad)
  unsigned short* myp = plds[wave];

  const int l0w = l0 + wave * 16;
  short8 qf[4];
  #pragma unroll
  for (int ks = 0; ks < 4; ++ks)
    qf[ks] = *reinterpret_cast<const short8*>(Q + (size_t)(l0w + lr) * DKD + ks * 32 + lc * 8);

  int offK[4], offV[4], ldsOff[4];
  #pragma unroll
  for (int j = 0; j < 4; ++j) {
    int ii = wave * 4 + j;                    // 0..15
    int rK = ii * 4 + (lane >> 4);            // K row 0..63
    int cK = (lane & 15) ^ (rK & 7);          // pre-swizzled 16B chunk
    offK[j] = rK * DKD + cK * 8;
    int vV = ii * 8 + (lane >> 3);            // V row 0..127
    int cV = (lane & 7) ^ (lane >> 3);        // (vV&7) == lane>>3
    offV[j] = vV * LL + cV * 8;
    ldsOff[j] = ii * 512;                     // 1KB per instr
  }

  f32x4 racc[8];
  #pragma unroll
  for (int vt = 0; vt < 8; ++vt) racc[vt] = (f32x4){0.f, 0.f, 0.f, 0.f};
  float lsum[4] = {0.f, 0.f, 0.f, 0.f};

  #pragma unroll
  for (int j = 0; j < 4; ++j) {
    glds16(K + (size_t)kbase * DKD + offK[j], &Ks[0][ldsOff[j]]);
    glds16(V + kbase + offV[j],               &Vs[0][ldsOff[j]]);
  }
  __syncthreads();

  const int sw = lr & 7;
  int buf = 0;
  for (int t = 0; t < TPS; ++t) {
    if (t + 1 < TPS) {
      int m1 = kbase + (t + 1) * KVBLK;
      #pragma unroll
      for (int j = 0; j < 4; ++j) {
        glds16(K + (size_t)m1 * DKD + offK[j], &Ks[buf ^ 1][ldsOff[j]]);
        glds16(V + m1 + offV[j],               &Vs[buf ^ 1][ldsOff[j]]);
      }
    }

    f32x4 sx[4];
    #pragma unroll
    for (int ct = 0; ct < 4; ++ct) {
      f32x4 acc = (f32x4){0.f, 0.f, 0.f, 0.f};
      #pragma unroll
      for (int ks = 0; ks < 4; ++ks) {
        short8 kf = *reinterpret_cast<const short8*>(
            &Ks[buf][(ct * 16 + lr) * DKD + ((ks * 4 + lc) ^ sw) * 8]);
        acc = __builtin_amdgcn_mfma_f32_16x16x32_bf16(qf[ks], kf, acc, 0, 0, 0);
      }
      sx[ct] = acc;
    }

    #pragma unroll
    for (int ct = 0; ct < 4; ++ct) {
      #pragma unroll
      for (int r = 0; r < 4; ++r) {
        float pv = __expf(sx[ct][r] - M);
        sx[ct][r] = pv;
        lsum[r] += pv;
      }
    }

    #pragma unroll
    for (int ct = 0; ct < 4; ++ct)
      #pragma unroll
      for (int r = 0; r < 4; ++r)
        myp[(lc * 4 + r) * 72 + ct * 16 + lr] = f2bf(sx[ct][r]);

    short8 pf[2];
    #pragma unroll
    for (int ks = 0; ks < 2; ++ks)
      pf[ks] = *reinterpret_cast<const short8*>(&myp[lr * 72 + ks * 32 + lc * 8]);

    #pragma unroll
    for (int vt = 0; vt < 8; ++vt) {
      #pragma unroll
      for (int ks = 0; ks < 2; ++ks) {
        short8 vf = *reinterpret_cast<const short8*>(
            &Vs[buf][(vt * 16 + lr) * KVBLK + ((ks * 4 + lc) ^ sw) * 8]);
        racc[vt] = __builtin_amdgcn_mfma_f32_16x16x32_bf16(pf[ks], vf, racc[vt], 0, 0, 0);
      }
    }

    __syncthreads();
    buf ^= 1;
  }

  #pragma unroll
  for (int r = 0; r < 4; ++r) {
    float v = lsum[r];
    #pragma unroll
    for (int msk = 8; msk; msk >>= 1) v += __shfl_xor(v, msk, 64);
    lsum[r] = v;
  }
  if (lr == 0) {
    #pragma unroll
    for (int r = 0; r < 4; ++r)
      ls[((size_t)s * 4 + bh) * LL + l0w + lc * 4 + r] = lsum[r];
  }

  unsigned short* Pb = pr + ((size_t)s * 4 + bh) * DVD * LL;
  #pragma unroll
  for (int vt = 0; vt < 8; ++vt) {
    ushort4v pk;
    #pragma unroll
    for (int r = 0; r < 4; ++r) pk[r] = f2bf(racc[vt][r]);
    *reinterpret_cast<ushort4v*>(Pb + (size_t)(vt * 16 + lr) * LL + l0w + lc * 4) = pk;
  }
}

// ---------------------------------------------------------------------------
// Kernel 3: split-K combine + transpose: Rt[b][l][c] bf16 = (pr0+pr1)*invL.
// grid (128 l-tiles of 32, 8 c-tiles of 32, B)  block 256.
// ---------------------------------------------------------------------------
__global__ __launch_bounds__(256) void mhsa_combine_kernel(
    const unsigned short* __restrict__ pr,
    const float* __restrict__ ls,
    unsigned short* __restrict__ Rt)
{
  const int l0 = blockIdx.x * 32;
  const int c0 = blockIdx.y * 32;
  const int b  = blockIdx.z;
  const int hh = c0 >> 7;                 // head (c0 is 32-aligned)

  __shared__ float Ts[32][33];
  __shared__ float invl[32];

  const int tid = threadIdx.x;
  const int tl  = tid & 31, tc = tid >> 5;   // tc 0..7

  if (tid < 32) {
    size_t bhl = (size_t)(b * NHD + hh) * LL + l0 + tid;
    invl[tid] = 1.f / (ls[bhl] + ls[(size_t)4 * LL + bhl]);
  }
  __syncthreads();

  const size_t sstride = (size_t)4 * DVD * LL;
  #pragma unroll
  for (int pp = 0; pp < 4; ++pp) {
    int cl = tc + pp * 8;
    int v  = (c0 & 127) + cl;
    size_t idx = ((size_t)(b * NHD + hh) * DVD + v) * LL + l0 + tl;
    Ts[cl][tl] = (bf2f(pr[idx]) + bf2f(pr[sstride + idx])) * invl[tl];
  }
  __syncthreads();

  unsigned short* Rb = Rt + (size_t)b * LL * CC;
  #pragma unroll
  for (int pp = 0; pp < 4; ++pp) {
    int ll = tc + pp * 8;
    Rb[(size_t)(l0 + ll) * CC + c0 + tl] = f2bf(Ts[tl][ll]);
  }
}

// ---------------------------------------------------------------------------
// Kernel 4: merge via MFMA: out[b][o][l] = Wm(bf16).Rt + bias + x residual.
// grid (64 l-tiles, 2 o-halves, B)  block 256 (4 waves) — projm clone.
// ---------------------------------------------------------------------------
__global__ __launch_bounds__(256) void mhsa_mergem_kernel(
    const unsigned short* __restrict__ Rt,
    const unsigned short* __restrict__ wmb,
    const float* __restrict__ bm,
    const float* __restrict__ x,
    float* __restrict__ out)
{
  const int lt0 = blockIdx.x * 64;
  const int oh  = blockIdx.y;            // 0/1 -> o in [oh*128, oh*128+128)
  const int b   = blockIdx.z;

  const unsigned short* W = wmb + (size_t)oh * 128 * 256;
  const unsigned short* X = Rt + (size_t)b * LL * CC;

  __shared__ unsigned short Ws[2][128 * 64];   // 2 x 16KB
  __shared__ unsigned short Xs[2][64 * 64];    // 2 x 8KB

  const int wave = threadIdx.x >> 6;
  const int lane = threadIdx.x & 63;
  const int lr = lane & 15, lc = lane >> 4;

  int offW[4], ldsW[4], offX[2], ldsX[2];
  #pragma unroll
  for (int j = 0; j < 4; ++j) {
    int ii = wave * 4 + j;
    int r  = ii * 8 + (lane >> 3);
    int c  = (lane & 7) ^ (lane >> 3);
    offW[j] = r * 256 + c * 8;
    ldsW[j] = ii * 512;
  }
  #pragma unroll
  for (int j = 0; j < 2; ++j) {
    int ii = wave * 2 + j;
    int r  = ii * 8 + (lane >> 3);
    int c  = (lane & 7) ^ (lane >> 3);
    offX[j] = (lt0 + r) * 256 + c * 8;
    ldsX[j] = ii * 512;
  }

  f32x4 acc[2][4];
  #pragma unroll
  for (int kt2 = 0; kt2 < 2; ++kt2)
    #pragma unroll
    for (int lt = 0; lt < 4; ++lt) acc[kt2][lt] = (f32x4){0.f, 0.f, 0.f, 0.f};

  #pragma unroll
  for (int j = 0; j < 4; ++j) glds16(W + offW[j], &Ws[0][ldsW[j]]);
  #pragma unroll
  for (int j = 0; j < 2; ++j) glds16(X + offX[j], &Xs[0][ldsX[j]]);
  __syncthreads();

  const int sw = lr & 7;
  int buf = 0;
  for (int step = 0; step < 4; ++step) {
    if (step < 3) {
      int c0 = (step + 1) * 64;
      #pragma unroll
      for (int j = 0; j < 4; ++j) glds16(W + c0 + offW[j], &Ws[buf ^ 1][ldsW[j]]);
      #pragma unroll
      for (int j = 0; j < 2; ++j) glds16(X + c0 + offX[j], &Xs[buf ^ 1][ldsX[j]]);
    }
    #pragma unroll
    for (int ks = 0; ks < 2; ++ks) {
      short8 af[2], bf_[4];
      #pragma unroll
      for (int kt2 = 0; kt2 < 2; ++kt2)
        af[kt2] = *reinterpret_cast<const short8*>(
            &Ws[buf][(wave * 32 + kt2 * 16 + lr) * 64 + ((ks * 4 + lc) ^ sw) * 8]);
      #pragma unroll
      for (int lt = 0; lt < 4; ++lt)
        bf_[lt] = *reinterpret_cast<const short8*>(
            &Xs[buf][(lt * 16 + lr) * 64 + ((ks * 4 + lc) ^ sw) * 8]);
      #pragma unroll
      for (int kt2 = 0; kt2 < 2; ++kt2)
        #pragma unroll
        for (int lt = 0; lt < 4; ++lt)
          acc[kt2][lt] = __builtin_amdgcn_mfma_f32_16x16x32_bf16(
              af[kt2], bf_[lt], acc[kt2][lt], 0, 0, 0);
    }
    __syncthreads();
    buf ^= 1;
  }

  // epilogue: bias + residual, fp32 store. o = oh*128 + wave*32 + kt2*16 + lc*4 + r
  #pragma unroll
  for (int kt2 = 0; kt2 < 2; ++kt2) {
    #pragma unroll
    for (int r = 0; r < 4; ++r) {
      int o = oh * 128 + wave * 32 + kt2 * 16 + lc * 4 + r;
      float bias = bm[o];
      #pragma unroll
      for (int lt = 0; lt < 4; ++lt) {
        size_t off = ((size_t)(b * CC + o)) * LL + lt0 + lt * 16 + lr;
        out[off] = acc[kt2][lt][r] + bias + x[off];
      }
    }
  }
}

// ---------------------------------------------------------------------------
extern "C" void kernel_launch(void* const* d_in, const int* in_sizes, int n_in,
                              void* d_out, int out_size, void* d_ws, size_t ws_size,
                              hipStream_t stream) {
  const float* x     = (const float*)d_in[0];
  const float* Wq    = (const float*)d_in[1];
  const float* bq    = (const float*)d_in[2];
  const float* Wk    = (const float*)d_in[3];
  const float* bk    = (const float*)d_in[4];
  const float* Wv    = (const float*)d_in[5];
  const float* bv    = (const float*)d_in[6];
  const float* scale = (const float*)d_in[7];
  const float* Wm    = (const float*)d_in[8];
  const float* bm    = (const float*)d_in[9];
  float* out = (float*)d_out;

  const size_t nqk = (size_t)BB * NHD * LL * DKD;            // 4.19M elems
  const size_t npr = (size_t)SPLITK * BB * NHD * DVD * LL;   // 8.39M elems
  unsigned short* qn = (unsigned short*)d_ws;
  unsigned short* kn = qn + nqk;
  unsigned short* vb = kn + nqk;
  unsigned short* pr = vb + nqk;                 // bf16 partials [s][bh][v][l]
  float* lsw = (float*)(pr + npr);               // f32 partial sums [s][bh][l]
  unsigned short* wmb = (unsigned short*)(lsw + (size_t)SPLITK * BB * NHD * LL);
  // Xt/wbf alias pr (dead until attn); Rt aliases qn (dead after attn)
  unsigned short* Xt  = pr;                      // 2.10M elems
  unsigned short* wbf = pr + (size_t)BB * LL * CC;
  unsigned short* Rt  = qn;                      // 2.10M elems <= nqk

  mhsa_pre_kernel<<<dim3(128, 8, 3), dim3(256), 0, stream>>>(
      x, Wq, Wk, Wv, Wm, Xt, wbf, wmb);
  mhsa_projm_kernel<<<dim3(LL / 64, BB * NHD, 3), dim3(256), 0, stream>>>(
      Xt, wbf, bq, bk, bv, scale, qn, kn, vb);
  mhsa_attn_kernel<<<dim3(LL / QBLK, BB * NHD, SPLITK), dim3(256), 0, stream>>>(
      qn, kn, vb, scale, pr, lsw);
  mhsa_combine_kernel<<<dim3(LL / 32, CC / 32, BB), dim3(256), 0, stream>>>(
      pr, lsw, Rt);
  mhsa_mergem_kernel<<<dim3(LL / 64, 2, BB), dim3(256), 0, stream>>>(
      Rt, wmb, bm, x, out);
}

// Round 33
// 90.661 us; speedup vs baseline: 4.3893x; 1.0532x over previous
//
#include <hip/hip_runtime.h>

// R33: attention occupancy push. KVBLK 64->32 (LDS 73->37KB, 4 blocks/CU fit)
// + SPLITK 2->4 (grid 512->1024 = 4/CU) => 4 waves/SIMD (was 2). V swizzle
// rebalanced for 4-chunk rows (chunk ^= (row>>1)&3, both-sides involution).
// ws-checked: falls back to SPLITK=2 deterministically if ws_size < ~60MB.
// pre/projm/combine/mergem unchanged from R25 (95.5us, passed).

// Problem constants
#define BB  2
#define CC  256
#define LL  4096   // 64*64 spatial tokens
#define NHD 2
#define DKD 128
#define DVD 128

#define QBLK   64
#define KVBLK  32

typedef short  short8  __attribute__((ext_vector_type(8)));
typedef float  f32x4   __attribute__((ext_vector_type(4)));
typedef unsigned short ushort4v __attribute__((ext_vector_type(4)));

__device__ __forceinline__ unsigned short f2bf(float f) {
  union { float f; unsigned u; } v; v.f = f;
  unsigned r = v.u + 0x7fffu + ((v.u >> 16) & 1u);   // RNE
  return (unsigned short)(r >> 16);
}
__device__ __forceinline__ float bf2f(unsigned short u) {
  union { unsigned u; float f; } v; v.u = ((unsigned)u) << 16;
  return v.f;
}
__device__ __forceinline__ void glds16(const unsigned short* g, unsigned short* l) {
  __builtin_amdgcn_global_load_lds(
      (const __attribute__((address_space(1))) void*)g,
      (__attribute__((address_space(3))) void*)l, 16, 0, 0);
}

// ---------------------------------------------------------------------------
// Kernel 0: precompute — z<2: transpose+convert x[b] fp32 [c][l] -> Xt bf16
// [l][c]; z==2,y==0: convert Wq/Wk/Wv -> wbf and Wm -> wmb (bf16).
// grid (128, 8, 3)  block 256. (unchanged from R25)
// ---------------------------------------------------------------------------
__global__ __launch_bounds__(256) void mhsa_pre_kernel(
    const float* __restrict__ x,
    const float* __restrict__ Wq, const float* __restrict__ Wk,
    const float* __restrict__ Wv, const float* __restrict__ Wm,
    unsigned short* __restrict__ Xt, unsigned short* __restrict__ wbf,
    unsigned short* __restrict__ wmb)
{
  const int z = blockIdx.z;
  if (z == 2) {
    if (blockIdx.y) return;
    int base = blockIdx.x * 2048 + threadIdx.x;
    #pragma unroll
    for (int i = 0; i < 8; ++i) {
      int idx = base + i * 256;
      if (idx < 196608) {
        int p = idx >> 16;
        int rem = idx & 65535;
        const float* W = p == 0 ? Wq : (p == 1 ? Wk : Wv);
        wbf[idx] = f2bf(W[rem]);
      } else {
        wmb[idx - 196608] = f2bf(Wm[idx - 196608]);
      }
    }
    return;
  }
  const int b  = z;
  const int l0 = blockIdx.x * 32, c0 = blockIdx.y * 32;
  __shared__ float Ts[32][33];
  const int tid = threadIdx.x;
  const int tl  = tid & 31, tc = tid >> 5;
  const float* xb = x + (size_t)b * CC * LL;
  #pragma unroll
  for (int pp = 0; pp < 4; ++pp) {
    int c = tc + pp * 8;
    Ts[c][tl] = xb[(size_t)(c0 + c) * LL + l0 + tl];
  }
  __syncthreads();
  unsigned short* Xb = Xt + (size_t)b * LL * CC;
  #pragma unroll
  for (int pp = 0; pp < 4; ++pp) {
    int l = tc + pp * 8;
    Xb[(size_t)(l0 + l) * CC + c0 + tl] = f2bf(Ts[tl][l]);
  }
}

// ---------------------------------------------------------------------------
// Kernel 1: QKV projections via MFMA (bf16 in, fp32 acc), fused l2-norm.
// grid (64 l-tiles, 4 bh, 3 p)  block 256 (4 waves). (unchanged from R24)
// ---------------------------------------------------------------------------
__global__ __launch_bounds__(256) void mhsa_projm_kernel(
    const unsigned short* __restrict__ Xt,
    const unsigned short* __restrict__ wbf,
    const float* __restrict__ bq, const float* __restrict__ bk,
    const float* __restrict__ bv, const float* __restrict__ scale,
    unsigned short* __restrict__ qn, unsigned short* __restrict__ kn,
    unsigned short* __restrict__ vb)
{
  const int lt0 = blockIdx.x * 64;
  const int bh  = blockIdx.y;
  const int p   = blockIdx.z;
  const int h   = bh & 1, b = bh >> 1;

  const unsigned short* W = wbf + ((size_t)p * 2 + h) * (128 * 256);
  const unsigned short* X = Xt + (size_t)b * LL * CC;
  const float* bias = (p == 0 ? bq : (p == 1 ? bk : bv)) + h * 128;

  __shared__ unsigned short Ws[2][128 * 64];
  __shared__ unsigned short Xs[2][64 * 64];
  __shared__ float red[4][64];

  const int wave = threadIdx.x >> 6;
  const int lane = threadIdx.x & 63;
  const int lr = lane & 15, lc = lane >> 4;

  int offW[4], ldsW[4], offX[2], ldsX[2];
  #pragma unroll
  for (int j = 0; j < 4; ++j) {
    int ii = wave * 4 + j;
    int r  = ii * 8 + (lane >> 3);
    int c  = (lane & 7) ^ (lane >> 3);
    offW[j] = r * 256 + c * 8;
    ldsW[j] = ii * 512;
  }
  #pragma unroll
  for (int j = 0; j < 2; ++j) {
    int ii = wave * 2 + j;
    int r  = ii * 8 + (lane >> 3);
    int c  = (lane & 7) ^ (lane >> 3);
    offX[j] = (lt0 + r) * 256 + c * 8;
    ldsX[j] = ii * 512;
  }

  f32x4 acc[2][4];
  #pragma unroll
  for (int kt2 = 0; kt2 < 2; ++kt2)
    #pragma unroll
    for (int lt = 0; lt < 4; ++lt) acc[kt2][lt] = (f32x4){0.f, 0.f, 0.f, 0.f};

  #pragma unroll
  for (int j = 0; j < 4; ++j) glds16(W + offW[j], &Ws[0][ldsW[j]]);
  #pragma unroll
  for (int j = 0; j < 2; ++j) glds16(X + offX[j], &Xs[0][ldsX[j]]);
  __syncthreads();

  const int sw = lr & 7;
  int buf = 0;
  for (int step = 0; step < 4; ++step) {
    if (step < 3) {
      int c0 = (step + 1) * 64;
      #pragma unroll
      for (int j = 0; j < 4; ++j) glds16(W + c0 + offW[j], &Ws[buf ^ 1][ldsW[j]]);
      #pragma unroll
      for (int j = 0; j < 2; ++j) glds16(X + c0 + offX[j], &Xs[buf ^ 1][ldsX[j]]);
    }
    #pragma unroll
    for (int ks = 0; ks < 2; ++ks) {
      short8 af[2], bf_[4];
      #pragma unroll
      for (int kt2 = 0; kt2 < 2; ++kt2)
        af[kt2] = *reinterpret_cast<const short8*>(
            &Ws[buf][(wave * 32 + kt2 * 16 + lr) * 64 + ((ks * 4 + lc) ^ sw) * 8]);
      #pragma unroll
      for (int lt = 0; lt < 4; ++lt)
        bf_[lt] = *reinterpret_cast<const short8*>(
            &Xs[buf][(lt * 16 + lr) * 64 + ((ks * 4 + lc) ^ sw) * 8]);
      #pragma unroll
      for (int kt2 = 0; kt2 < 2; ++kt2)
        #pragma unroll
        for (int lt = 0; lt < 4; ++lt)
          acc[kt2][lt] = __builtin_amdgcn_mfma_f32_16x16x32_bf16(
              af[kt2], bf_[lt], acc[kt2][lt], 0, 0, 0);
    }
    __syncthreads();
    buf ^= 1;
  }

  #pragma unroll
  for (int kt2 = 0; kt2 < 2; ++kt2)
    #pragma unroll
    for (int r = 0; r < 4; ++r) {
      float bsv = bias[wave * 32 + kt2 * 16 + lc * 4 + r];
      #pragma unroll
      for (int lt = 0; lt < 4; ++lt) acc[kt2][lt][r] += bsv;
    }

  if (p < 2) {
    float s[4];
    #pragma unroll
    for (int lt = 0; lt < 4; ++lt) {
      float v = 0.f;
      #pragma unroll
      for (int kt2 = 0; kt2 < 2; ++kt2)
        #pragma unroll
        for (int r = 0; r < 4; ++r) v += acc[kt2][lt][r] * acc[kt2][lt][r];
      v += __shfl_xor(v, 16, 64);
      v += __shfl_xor(v, 32, 64);
      s[lt] = v;
    }
    if (lc == 0) {
      #pragma unroll
      for (int lt = 0; lt < 4; ++lt) red[wave][lt * 16 + lr] = s[lt];
    }
    __syncthreads();
    float sq = sqrtf(scale[h]);
    unsigned short* out = (p == 0 ? qn : kn) + (size_t)bh * LL * DKD;
    #pragma unroll
    for (int lt = 0; lt < 4; ++lt) {
      int l = lt * 16 + lr;
      float sum = red[0][l] + red[1][l] + red[2][l] + red[3][l];
      float nv = sq / fmaxf(sqrtf(sum), 1e-6f);
      #pragma unroll
      for (int kt2 = 0; kt2 < 2; ++kt2) {
        ushort4v pk;
        #pragma unroll
        for (int r = 0; r < 4; ++r) pk[r] = f2bf(acc[kt2][lt][r] * nv);
        *reinterpret_cast<ushort4v*>(
            out + (size_t)(lt0 + l) * DKD + wave * 32 + kt2 * 16 + lc * 4) = pk;
      }
    }
  } else {
    unsigned short* outv = vb + (size_t)bh * DVD * LL;
    #pragma unroll
    for (int kt2 = 0; kt2 < 2; ++kt2)
      #pragma unroll
      for (int r = 0; r < 4; ++r)
        #pragma unroll
        for (int lt = 0; lt < 4; ++lt)
          outv[(size_t)(wave * 32 + kt2 * 16 + lc * 4 + r) * LL + lt0 + lt * 16 + lr]
              = f2bf(acc[kt2][lt][r]);
  }
}

// ---------------------------------------------------------------------------
// Kernel 2: flash attention, KVBLK=32, runtime split count ns (2 or 4).
// grid (64, 4, ns) block 256 (4 waves). LDS 37KB -> 4 blocks/CU; ns=4 gives
// 1024 blocks = 4/CU = 16 waves/CU = 4 waves/SIMD.
// K swizzle: chunk ^= row&7 (16 chunks/row). V swizzle: chunk ^= (row>>1)&3
// (4 chunks/row, balanced 8 bank-bases). STATIC-MAX softmax (M=scale[h]).
// ---------------------------------------------------------------------------
__global__ __launch_bounds__(256) void mhsa_attn_kernel(
    const unsigned short* __restrict__ qn,
    const unsigned short* __restrict__ kn,
    const unsigned short* __restrict__ vb,
    const float* __restrict__ scale,
    unsigned short* __restrict__ pr,
    float* __restrict__ ls,
    int kchunk)                              // LL/ns keys per split
{
  const int wgid = (blockIdx.z * gridDim.y + blockIdx.y) * gridDim.x + blockIdx.x;
  const int xcd  = wgid & 7;
  const int slot = wgid >> 3;                 // 0..(8*ns-1)... 0..127 at ns=4
  const int bh   = xcd >> 1;                  // 0..3
  const int qt   = ((xcd & 1) << 5) | (slot & 31);   // 0..63
  const int s    = slot >> 5;                 // split 0..ns-1
  const int l0   = qt * QBLK;
  const int kbase = s * kchunk;
  const int tps  = kchunk / KVBLK;

  const int wave = threadIdx.x >> 6;
  const int lane = threadIdx.x & 63;
  const int lr   = lane & 15;
  const int lc   = lane >> 4;

  const unsigned short* Q = qn + (size_t)bh * LL * DKD;
  const unsigned short* K = kn + (size_t)bh * LL * DKD;
  const unsigned short* V = vb + (size_t)bh * DVD * LL;
  const float M = scale[bh & 1];              // exact row max of S

  __shared__ unsigned short Ks[2][KVBLK * DKD];   // 2 x 8KB
  __shared__ unsigned short Vs[2][DVD * KVBLK];   // 2 x 8KB
  __shared__ unsigned short plds[4][16 * 40];     // per-wave P tile (+pad)
  unsigned short* myp = plds[wave];

  const int l0w = l0 + wave * 16;
  short8 qf[4];
  #pragma unroll
  for (int ks = 0; ks < 4; ++ks)
    qf[ks] = *reinterpret_cast<const short8*>(Q + (size_t)(l0w + lr) * DKD + ks * 32 + lc * 8);

  // staging offsets (u16 units); 2 instrs/wave per K and per V buffer
  int offK[2], offV[2], ldsOff[2];
  #pragma unroll
  for (int j = 0; j < 2; ++j) {
    int ii = wave * 2 + j;                    // 0..7
    int rK = ii * 4 + (lane >> 4);            // K row 0..31 (256B rows)
    int cK = (lane & 15) ^ (rK & 7);          // pre-swizzled 16B chunk
    offK[j] = rK * DKD + cK * 8;
    int vV = ii * 16 + (lane >> 2);           // V row 0..127 (64B rows)
    int cV = (lane & 3) ^ ((vV >> 1) & 3);    // pre-swizzled chunk (4/row)
    offV[j] = vV * LL + cV * 8;
    ldsOff[j] = ii * 512;                     // 1KB per instr
  }

  f32x4 racc[8];
  #pragma unroll
  for (int vt = 0; vt < 8; ++vt) racc[vt] = (f32x4){0.f, 0.f, 0.f, 0.f};
  float lsum[4] = {0.f, 0.f, 0.f, 0.f};

  #pragma unroll
  for (int j = 0; j < 2; ++j) {
    glds16(K + (size_t)kbase * DKD + offK[j], &Ks[0][ldsOff[j]]);
    glds16(V + kbase + offV[j],               &Vs[0][ldsOff[j]]);
  }
  __syncthreads();

  const int sw  = lr & 7;
  const int swV = (lr >> 1) & 3;
  int buf = 0;
  for (int t = 0; t < tps; ++t) {
    if (t + 1 < tps) {
      int m1 = kbase + (t + 1) * KVBLK;
      #pragma unroll
      for (int j = 0; j < 2; ++j) {
        glds16(K + (size_t)m1 * DKD + offK[j], &Ks[buf ^ 1][ldsOff[j]]);
        glds16(V + m1 + offV[j],               &Vs[buf ^ 1][ldsOff[j]]);
      }
    }

    // ---- S tile: 16 q-rows x 32 keys ----
    f32x4 sx[2];
    #pragma unroll
    for (int ct = 0; ct < 2; ++ct) {
      f32x4 acc = (f32x4){0.f, 0.f, 0.f, 0.f};
      #pragma unroll
      for (int ks = 0; ks < 4; ++ks) {
        short8 kf = *reinterpret_cast<const short8*>(
            &Ks[buf][(ct * 16 + lr) * DKD + ((ks * 4 + lc) ^ sw) * 8]);
        acc = __builtin_amdgcn_mfma_f32_16x16x32_bf16(qf[ks], kf, acc, 0, 0, 0);
      }
      sx[ct] = acc;
    }

    // ---- P = exp(S - M) ----
    #pragma unroll
    for (int ct = 0; ct < 2; ++ct) {
      #pragma unroll
      for (int r = 0; r < 4; ++r) {
        float pv = __expf(sx[ct][r] - M);
        sx[ct][r] = pv;
        lsum[r] += pv;
      }
    }

    // ---- P -> per-wave LDS (bf16), D-frag -> A-frag ----
    #pragma unroll
    for (int ct = 0; ct < 2; ++ct)
      #pragma unroll
      for (int r = 0; r < 4; ++r)
        myp[(lc * 4 + r) * 40 + ct * 16 + lr] = f2bf(sx[ct][r]);

    short8 pf = *reinterpret_cast<const short8*>(&myp[lr * 40 + lc * 8]);

    // ---- PV: racc[vt] += P[16x32] . V^T[32x16] ----
    #pragma unroll
    for (int vt = 0; vt < 8; ++vt) {
      short8 vf = *reinterpret_cast<const short8*>(
          &Vs[buf][(vt * 16 + lr) * KVBLK + (lc ^ swV) * 8]);
      racc[vt] = __builtin_amdgcn_mfma_f32_16x16x32_bf16(pf, vf, racc[vt], 0, 0, 0);
    }

    __syncthreads();
    buf ^= 1;
  }

  // ---- row-sum reduce across the 16 key-lanes; write partial lsum ----
  #pragma unroll
  for (int r = 0; r < 4; ++r) {
    float v = lsum[r];
    #pragma unroll
    for (int msk = 8; msk; msk >>= 1) v += __shfl_xor(v, msk, 64);
    lsum[r] = v;
  }
  if (lr == 0) {
    #pragma unroll
    for (int r = 0; r < 4; ++r)
      ls[((size_t)s * 4 + bh) * LL + l0w + lc * 4 + r] = lsum[r];
  }

  unsigned short* Pb = pr + ((size_t)s * 4 + bh) * DVD * LL;
  #pragma unroll
  for (int vt = 0; vt < 8; ++vt) {
    ushort4v pk;
    #pragma unroll
    for (int r = 0; r < 4; ++r) pk[r] = f2bf(racc[vt][r]);
    *reinterpret_cast<ushort4v*>(Pb + (size_t)(vt * 16 + lr) * LL + l0w + lc * 4) = pk;
  }
}

// ---------------------------------------------------------------------------
// Kernel 3: split-K combine + transpose: Rt[b][l][c] = (sum_s pr_s)*invL.
// grid (128 l-tiles of 32, 8 c-tiles of 32, B)  block 256; ns runtime.
// ---------------------------------------------------------------------------
__global__ __launch_bounds__(256) void mhsa_combine_kernel(
    const unsigned short* __restrict__ pr,
    const float* __restrict__ ls,
    unsigned short* __restrict__ Rt,
    int ns)
{
  const int l0 = blockIdx.x * 32;
  const int c0 = blockIdx.y * 32;
  const int b  = blockIdx.z;
  const int hh = c0 >> 7;

  __shared__ float Ts[32][33];
  __shared__ float invl[32];

  const int tid = threadIdx.x;
  const int tl  = tid & 31, tc = tid >> 5;

  if (tid < 32) {
    size_t bhl = (size_t)(b * NHD + hh) * LL + l0 + tid;
    float t = 0.f;
    for (int s = 0; s < ns; ++s) t += ls[bhl + (size_t)s * 4 * LL];
    invl[tid] = 1.f / t;
  }
  __syncthreads();

  const size_t sstride = (size_t)4 * DVD * LL;
  #pragma unroll
  for (int pp = 0; pp < 4; ++pp) {
    int cl = tc + pp * 8;
    int v  = (c0 & 127) + cl;
    size_t idx = ((size_t)(b * NHD + hh) * DVD + v) * LL + l0 + tl;
    float a = 0.f;
    for (int s = 0; s < ns; ++s) a += bf2f(pr[idx + (size_t)s * sstride]);
    Ts[cl][tl] = a * invl[tl];
  }
  __syncthreads();

  unsigned short* Rb = Rt + (size_t)b * LL * CC;
  #pragma unroll
  for (int pp = 0; pp < 4; ++pp) {
    int ll = tc + pp * 8;
    Rb[(size_t)(l0 + ll) * CC + c0 + tl] = f2bf(Ts[tl][ll]);
  }
}

// ---------------------------------------------------------------------------
// Kernel 4: merge via MFMA: out[b][o][l] = Wm(bf16).Rt + bias + x residual.
// grid (64 l-tiles, 2 o-halves, B)  block 256 (4 waves). (unchanged from R25)
// ---------------------------------------------------------------------------
__global__ __launch_bounds__(256) void mhsa_mergem_kernel(
    const unsigned short* __restrict__ Rt,
    const unsigned short* __restrict__ wmb,
    const float* __restrict__ bm,
    const float* __restrict__ x,
    float* __restrict__ out)
{
  const int lt0 = blockIdx.x * 64;
  const int oh  = blockIdx.y;
  const int b   = blockIdx.z;

  const unsigned short* W = wmb + (size_t)oh * 128 * 256;
  const unsigned short* X = Rt + (size_t)b * LL * CC;

  __shared__ unsigned short Ws[2][128 * 64];
  __shared__ unsigned short Xs[2][64 * 64];

  const int wave = threadIdx.x >> 6;
  const int lane = threadIdx.x & 63;
  const int lr = lane & 15, lc = lane >> 4;

  int offW[4], ldsW[4], offX[2], ldsX[2];
  #pragma unroll
  for (int j = 0; j < 4; ++j) {
    int ii = wave * 4 + j;
    int r  = ii * 8 + (lane >> 3);
    int c  = (lane & 7) ^ (lane >> 3);
    offW[j] = r * 256 + c * 8;
    ldsW[j] = ii * 512;
  }
  #pragma unroll
  for (int j = 0; j < 2; ++j) {
    int ii = wave * 2 + j;
    int r  = ii * 8 + (lane >> 3);
    int c  = (lane & 7) ^ (lane >> 3);
    offX[j] = (lt0 + r) * 256 + c * 8;
    ldsX[j] = ii * 512;
  }

  f32x4 acc[2][4];
  #pragma unroll
  for (int kt2 = 0; kt2 < 2; ++kt2)
    #pragma unroll
    for (int lt = 0; lt < 4; ++lt) acc[kt2][lt] = (f32x4){0.f, 0.f, 0.f, 0.f};

  #pragma unroll
  for (int j = 0; j < 4; ++j) glds16(W + offW[j], &Ws[0][ldsW[j]]);
  #pragma unroll
  for (int j = 0; j < 2; ++j) glds16(X + offX[j], &Xs[0][ldsX[j]]);
  __syncthreads();

  const int sw = lr & 7;
  int buf = 0;
  for (int step = 0; step < 4; ++step) {
    if (step < 3) {
      int c0 = (step + 1) * 64;
      #pragma unroll
      for (int j = 0; j < 4; ++j) glds16(W + c0 + offW[j], &Ws[buf ^ 1][ldsW[j]]);
      #pragma unroll
      for (int j = 0; j < 2; ++j) glds16(X + c0 + offX[j], &Xs[buf ^ 1][ldsX[j]]);
    }
    #pragma unroll
    for (int ks = 0; ks < 2; ++ks) {
      short8 af[2], bf_[4];
      #pragma unroll
      for (int kt2 = 0; kt2 < 2; ++kt2)
        af[kt2] = *reinterpret_cast<const short8*>(
            &Ws[buf][(wave * 32 + kt2 * 16 + lr) * 64 + ((ks * 4 + lc) ^ sw) * 8]);
      #pragma unroll
      for (int lt = 0; lt < 4; ++lt)
        bf_[lt] = *reinterpret_cast<const short8*>(
            &Xs[buf][(lt * 16 + lr) * 64 + ((ks * 4 + lc) ^ sw) * 8]);
      #pragma unroll
      for (int kt2 = 0; kt2 < 2; ++kt2)
        #pragma unroll
        for (int lt = 0; lt < 4; ++lt)
          acc[kt2][lt] = __builtin_amdgcn_mfma_f32_16x16x32_bf16(
              af[kt2], bf_[lt], acc[kt2][lt], 0, 0, 0);
    }
    __syncthreads();
    buf ^= 1;
  }

  #pragma unroll
  for (int kt2 = 0; kt2 < 2; ++kt2) {
    #pragma unroll
    for (int r = 0; r < 4; ++r) {
      int o = oh * 128 + wave * 32 + kt2 * 16 + lc * 4 + r;
      float bias = bm[o];
      #pragma unroll
      for (int lt = 0; lt < 4; ++lt) {
        size_t off = ((size_t)(b * CC + o)) * LL + lt0 + lt * 16 + lr;
        out[off] = acc[kt2][lt][r] + bias + x[off];
      }
    }
  }
}

// ---------------------------------------------------------------------------
extern "C" void kernel_launch(void* const* d_in, const int* in_sizes, int n_in,
                              void* d_out, int out_size, void* d_ws, size_t ws_size,
                              hipStream_t stream) {
  const float* x     = (const float*)d_in[0];
  const float* Wq    = (const float*)d_in[1];
  const float* bq    = (const float*)d_in[2];
  const float* Wk    = (const float*)d_in[3];
  const float* bk    = (const float*)d_in[4];
  const float* Wv    = (const float*)d_in[5];
  const float* bv    = (const float*)d_in[6];
  const float* scale = (const float*)d_in[7];
  const float* Wm    = (const float*)d_in[8];
  const float* bm    = (const float*)d_in[9];
  float* out = (float*)d_out;

  const size_t nqk    = (size_t)BB * NHD * LL * DKD;       // 4.19M elems
  const size_t prPlane = (size_t)BB * NHD * DVD * LL;      // 4.19M elems/split
  const size_t lsPlane = (size_t)BB * NHD * LL;            // 65536 floats/split

  // choose split count by workspace budget (deterministic: ws_size constant)
  size_t need4 = 3 * nqk * 2 + 4 * prPlane * 2 + 4 * lsPlane * 4 + 65536 * 2;
  const int ns = (ws_size >= need4) ? 4 : 2;
  const int kchunk = LL / ns;

  unsigned short* qn = (unsigned short*)d_ws;
  unsigned short* kn = qn + nqk;
  unsigned short* vb = kn + nqk;
  unsigned short* pr = vb + nqk;                       // bf16 [s][bh][v][l]
  float* lsw = (float*)(pr + (size_t)ns * prPlane);    // f32 [s][bh][l]
  unsigned short* wmb = (unsigned short*)(lsw + (size_t)ns * lsPlane);
  // Xt/wbf alias pr (dead until attn); Rt aliases qn (dead after attn)
  unsigned short* Xt  = pr;
  unsigned short* wbf = pr + (size_t)BB * LL * CC;
  unsigned short* Rt  = qn;

  mhsa_pre_kernel<<<dim3(128, 8, 3), dim3(256), 0, stream>>>(
      x, Wq, Wk, Wv, Wm, Xt, wbf, wmb);
  mhsa_projm_kernel<<<dim3(LL / 64, BB * NHD, 3), dim3(256), 0, stream>>>(
      Xt, wbf, bq, bk, bv, scale, qn, kn, vb);
  mhsa_attn_kernel<<<dim3(LL / QBLK, BB * NHD, ns), dim3(256), 0, stream>>>(
      qn, kn, vb, scale, pr, lsw, kchunk);
  mhsa_combine_kernel<<<dim3(LL / 32, CC / 32, BB), dim3(256), 0, stream>>>(
      pr, lsw, Rt, ns);
  mhsa_mergem_kernel<<<dim3(LL / 64, 2, BB), dim3(256), 0, stream>>>(
      Rt, wmb, bm, x, out);
}